// Round 1
// baseline (1160.961 us; speedup 1.0000x reference)
//
#include <hip/hip_runtime.h>
#include <math.h>

// ---------------------------------------------------------------------------
// RecurrentGCN: 2x GConvLSTM(Cheb K=5) + ReLU + collapsed 4-linear head.
// Simplifications (H=C=0 at t=0):
//   cheb(H=0) == bh (bias only); forget gate is dead (F*C==0);
//   head linears compose to single affine w_eff[32], b_eff.
// Pipeline per call:
//   CSR build (deg/counts -> scan -> scatter) ; weight prep ;
//   per layer: 4 props (Cheb recurrence) + fused gates GEMM ; head dot.
// ---------------------------------------------------------------------------

#define TPB 256

// ---- edge pass 1: degree (by src) + in-degree counts (by dst) -------------
__global__ __launch_bounds__(TPB) void k_edge_pass1(
    const int* __restrict__ ei, const float* __restrict__ ew,
    float* __restrict__ deg, int* __restrict__ counts, int E) {
  int i = blockIdx.x * TPB + threadIdx.x;
  if (i >= E) return;
  int s = ei[i];
  int d = ei[E + i];
  atomicAdd(&deg[s], ew[i]);
  atomicAdd(&counts[d], 1);
}

__global__ __launch_bounds__(TPB) void k_dinv(
    const float* __restrict__ deg, float* __restrict__ dinv, int n) {
  int i = blockIdx.x * TPB + threadIdx.x;
  if (i >= n) return;
  float dg = deg[i];
  dinv[i] = (dg > 0.f) ? 1.0f / sqrtf(fmaxf(dg, 1e-12f)) : 0.f;
}

// ---- 3-kernel exclusive scan of counts[n] ---------------------------------
__global__ __launch_bounds__(TPB) void k_scan1(
    const int* __restrict__ counts, int* __restrict__ excl,
    int* __restrict__ bsum, int n) {
  __shared__ int sh[TPB];
  int tid = threadIdx.x;
  int i = blockIdx.x * TPB + tid;
  int v = (i < n) ? counts[i] : 0;
  sh[tid] = v;
  __syncthreads();
  for (int off = 1; off < TPB; off <<= 1) {
    int t = (tid >= off) ? sh[tid - off] : 0;
    __syncthreads();
    sh[tid] += t;
    __syncthreads();
  }
  if (i < n) excl[i] = sh[tid] - v;
  if (tid == TPB - 1) bsum[blockIdx.x] = sh[TPB - 1];
}

__global__ __launch_bounds__(TPB) void k_scan2(int* __restrict__ bsum, int nb) {
  __shared__ int sh[TPB];
  int tid = threadIdx.x;
  int v = (tid < nb) ? bsum[tid] : 0;
  sh[tid] = v;
  __syncthreads();
  for (int off = 1; off < TPB; off <<= 1) {
    int t = (tid >= off) ? sh[tid - off] : 0;
    __syncthreads();
    sh[tid] += t;
    __syncthreads();
  }
  if (tid < nb) bsum[tid] = sh[tid] - v;
}

__global__ __launch_bounds__(TPB) void k_scan3(
    const int* __restrict__ excl, const int* __restrict__ bsum,
    int* __restrict__ rp, int* __restrict__ wp, int n, int E) {
  int i = blockIdx.x * TPB + threadIdx.x;
  if (i < n) {
    int r = excl[i] + bsum[i >> 8];
    rp[i] = r;
    wp[i] = r;
  }
  if (i == 0) rp[n] = E;
}

// ---- edge pass 2: scatter into CSR (by dst) with fused norm ---------------
__global__ __launch_bounds__(TPB) void k_edge_pass2(
    const int* __restrict__ ei, const float* __restrict__ ew,
    const float* __restrict__ dinv, int* __restrict__ wp,
    int* __restrict__ csrc, float* __restrict__ cnorm, int E) {
  int i = blockIdx.x * TPB + threadIdx.x;
  if (i >= E) return;
  int s = ei[i];
  int d = ei[E + i];
  float nv = -dinv[s] * ew[i] * dinv[d];
  int pos = atomicAdd(&wp[d], 1);
  csrc[pos] = s;
  cnorm[pos] = nv;
}

// ---- sparse prop: y[dst] = alpha * sum_e norm_e * x[src_e] + beta * prev --
// thread = (node, feature); 8 nodes per 256-thread block.
__global__ __launch_bounds__(TPB) void k_prop(
    const float* __restrict__ xin, const int* __restrict__ rp,
    const int* __restrict__ csrc, const float* __restrict__ cnorm,
    const float* __restrict__ prev, float alpha, float beta,
    float* __restrict__ yout, int n) {
  int node = blockIdx.x * 8 + (threadIdx.x >> 5);
  int f = threadIdx.x & 31;
  if (node >= n) return;
  int b = rp[node], e = rp[node + 1];
  float acc = 0.f;
  for (int t = b; t < e; ++t) {
    acc = fmaf(cnorm[t], xin[csrc[t] * 32 + f], acc);
  }
  float r = alpha * acc;
  if (prev != nullptr) r = fmaf(beta, prev[node * 32 + f], r);
  yout[node * 32 + f] = r;
}

// ---- weight prep: Wt[k][j] (k=kk*32+i in 0..159, j=g3*32+h in 0..95) ------
// gates kept: g3=0 -> i (gate 0), g3=1 -> c (gate 2), g3=2 -> o (gate 3)
__global__ __launch_bounds__(TPB) void k_build_wt(
    const float* __restrict__ Wx, const float* __restrict__ bx,
    const float* __restrict__ bh, const float* __restrict__ bb,
    float* __restrict__ Wt, float* __restrict__ be) {
  int idx = blockIdx.x * TPB + threadIdx.x;
  if (idx < 160 * 96) {
    int k = idx / 96, j = idx % 96;
    int kk = k >> 5, i = k & 31;
    int g3 = j >> 5, h = j & 31;
    int g = (g3 == 0) ? 0 : (g3 == 1 ? 2 : 3);
    Wt[idx] = Wx[((g * 5 + kk) * 32 + i) * 32 + h];
  }
  if (idx < 96) {
    int g3 = idx >> 5, h = idx & 31;
    int g = (g3 == 0) ? 0 : (g3 == 1 ? 2 : 3);
    be[idx] = bx[g * 32 + h] + bh[g * 32 + h] + bb[g * 32 + h];
  }
}

// ---- head collapse: w_eff = hw1@hw2@hw3@hw4, b_eff similarly --------------
__global__ void k_head_setup(
    const float* __restrict__ hw1, const float* __restrict__ hb1,
    const float* __restrict__ hw2, const float* __restrict__ hb2,
    const float* __restrict__ hw3, const float* __restrict__ hb3,
    const float* __restrict__ hw4, const float* __restrict__ hb4,
    float* __restrict__ weff) {
  int a = threadIdx.x;
  if (a < 32) {
    float w12[8];
    for (int c = 0; c < 8; ++c) {
      float s = 0.f;
      for (int b = 0; b < 16; ++b) s += hw1[a * 16 + b] * hw2[b * 8 + c];
      w12[c] = s;
    }
    float w123[4];
    for (int d = 0; d < 4; ++d) {
      float s = 0.f;
      for (int c = 0; c < 8; ++c) s += w12[c] * hw3[c * 4 + d];
      w123[d] = s;
    }
    float s = 0.f;
    for (int d = 0; d < 4; ++d) s += w123[d] * hw4[d];
    weff[a] = s;
  }
  if (a == 32) {
    float t2[8];
    for (int c = 0; c < 8; ++c) {
      float s = hb2[c];
      for (int b = 0; b < 16; ++b) s += hb1[b] * hw2[b * 8 + c];
      t2[c] = s;
    }
    float t3[4];
    for (int d = 0; d < 4; ++d) {
      float s = hb3[d];
      for (int c = 0; c < 8; ++c) s += t2[c] * hw3[c * 4 + d];
      t3[d] = s;
    }
    float s = hb4[0];
    for (int d = 0; d < 4; ++d) s += t3[d] * hw4[d];
    weff[32] = s;
  }
}

// ---- fused gates: [50000 x 160] @ [160 x 96] + LSTM gate math + ReLU ------
// block: 192 threads, 32 nodes. thread owns (j = tid%96, node-group tid/96 of 16).
__global__ __launch_bounds__(192) void k_gates(
    const float* __restrict__ T0, const float* __restrict__ T1,
    const float* __restrict__ T2, const float* __restrict__ T3,
    const float* __restrict__ T4, const float* __restrict__ Wt,
    const float* __restrict__ be, const float* __restrict__ wc2,
    float* __restrict__ Hout, int n) {
  __shared__ float Tlds[32 * 164];   // 32 nodes x 160 cols, padded
  __shared__ float preLds[32 * 97];  // 32 nodes x 96 gate pre-acts, padded
  int tid = threadIdx.x;
  int base = blockIdx.x * 32;

  for (int idx = tid; idx < 5 * 1024; idx += 192) {
    int tsel = idx >> 10;
    int rem = idx & 1023;
    int node = rem >> 5, fi = rem & 31;
    int gn = base + node;
    const float* Tp = (tsel == 0) ? T0 : (tsel == 1) ? T1 : (tsel == 2) ? T2
                      : (tsel == 3) ? T3 : T4;
    Tlds[node * 164 + tsel * 32 + fi] = (gn < n) ? Tp[gn * 32 + fi] : 0.f;
  }
  __syncthreads();

  int j = tid % 96;
  int ng = tid / 96;
  float acc[16];
#pragma unroll
  for (int i = 0; i < 16; ++i) acc[i] = 0.f;

  for (int k4 = 0; k4 < 40; ++k4) {
    int k = k4 * 4;
    float w0 = Wt[(k + 0) * 96 + j];
    float w1 = Wt[(k + 1) * 96 + j];
    float w2 = Wt[(k + 2) * 96 + j];
    float w3 = Wt[(k + 3) * 96 + j];
#pragma unroll
    for (int i = 0; i < 16; ++i) {
      const float4 t =
          *reinterpret_cast<const float4*>(&Tlds[(ng * 16 + i) * 164 + k]);
      float a = acc[i];
      a = fmaf(t.x, w0, a);
      a = fmaf(t.y, w1, a);
      a = fmaf(t.z, w2, a);
      a = fmaf(t.w, w3, a);
      acc[i] = a;
    }
  }

  float bej = be[j];
#pragma unroll
  for (int i = 0; i < 16; ++i) preLds[(ng * 16 + i) * 97 + j] = acc[i] + bej;
  __syncthreads();

  for (int idx = tid; idx < 1024; idx += 192) {
    int node = idx >> 5, h = idx & 31;
    int gn = base + node;
    if (gn >= n) continue;
    float pi = preLds[node * 97 + h];
    float pc = preLds[node * 97 + 32 + h];
    float po = preLds[node * 97 + 64 + h];
    float I = 1.f / (1.f + expf(-pi));
    float Cn = I * tanhf(pc);
    float O = 1.f / (1.f + expf(-(po + wc2[h] * Cn)));
    Hout[gn * 32 + h] = fmaxf(O * tanhf(Cn), 0.f);
  }
}

// ---- head: out[n] = H2[n,:] . w_eff + b_eff -------------------------------
__global__ __launch_bounds__(TPB) void k_head(
    const float* __restrict__ H, const float* __restrict__ weff,
    float* __restrict__ out, int n) {
  int i = blockIdx.x * TPB + threadIdx.x;
  if (i >= n) return;
  const float4* hp = reinterpret_cast<const float4*>(H + i * 32);
  float s = weff[32];
#pragma unroll
  for (int q = 0; q < 8; ++q) {
    float4 v = hp[q];
    s = fmaf(v.x, weff[q * 4 + 0], s);
    s = fmaf(v.y, weff[q * 4 + 1], s);
    s = fmaf(v.z, weff[q * 4 + 2], s);
    s = fmaf(v.w, weff[q * 4 + 3], s);
  }
  out[i] = s;
}

extern "C" void kernel_launch(void* const* d_in, const int* in_sizes, int n_in,
                              void* d_out, int out_size, void* d_ws,
                              size_t ws_size, hipStream_t stream) {
  const float* x = (const float*)d_in[0];
  const int* ei = (const int*)d_in[1];
  const float* ew = (const float*)d_in[2];
  const float* l1_Wx = (const float*)d_in[3];
  const float* l1_bx = (const float*)d_in[4];
  const float* l1_bh = (const float*)d_in[6];
  const float* l1_wc = (const float*)d_in[7];
  const float* l1_b = (const float*)d_in[8];
  const float* l2_Wx = (const float*)d_in[9];
  const float* l2_bx = (const float*)d_in[10];
  const float* l2_bh = (const float*)d_in[12];
  const float* l2_wc = (const float*)d_in[13];
  const float* l2_b = (const float*)d_in[14];
  const float* hw1 = (const float*)d_in[15];
  const float* hb1 = (const float*)d_in[16];
  const float* hw2 = (const float*)d_in[17];
  const float* hb2 = (const float*)d_in[18];
  const float* hw3 = (const float*)d_in[19];
  const float* hb3 = (const float*)d_in[20];
  const float* hw4 = (const float*)d_in[21];
  const float* hb4 = (const float*)d_in[22];

  const int N = in_sizes[0] / 32;
  const int E = in_sizes[1] / 2;

  // workspace carve-out (256B aligned)
  char* w = (char*)d_ws;
  auto alloc = [&](size_t bytes) -> void* {
    void* p = (void*)w;
    w += (bytes + 255) & ~(size_t)255;
    return p;
  };
  float* deg = (float*)alloc((size_t)N * 4);
  int* counts = (int*)alloc((size_t)N * 4);
  float* dinv = (float*)alloc((size_t)N * 4);
  int* rp = (int*)alloc((size_t)(N + 1) * 4);
  int* wp = (int*)alloc((size_t)N * 4);
  int* excl = (int*)alloc((size_t)N * 4);
  int* bsum = (int*)alloc(256 * 4);
  int* csrc = (int*)alloc((size_t)E * 4);
  float* cnorm = (float*)alloc((size_t)E * 4);
  float* T1 = (float*)alloc((size_t)N * 32 * 4);
  float* T2 = (float*)alloc((size_t)N * 32 * 4);
  float* T3 = (float*)alloc((size_t)N * 32 * 4);
  float* T4 = (float*)alloc((size_t)N * 32 * 4);
  float* H1 = (float*)alloc((size_t)N * 32 * 4);
  float* H2 = (float*)alloc((size_t)N * 32 * 4);
  float* Wt1 = (float*)alloc(160 * 96 * 4);
  float* be1 = (float*)alloc(96 * 4);
  float* Wt2 = (float*)alloc(160 * 96 * 4);
  float* be2 = (float*)alloc(96 * 4);
  float* weff = (float*)alloc(40 * 4);

  const int gE = (E + TPB - 1) / TPB;
  const int gN = (N + TPB - 1) / TPB;
  const int gP = (N + 7) / 8;
  const int gG = (N + 31) / 32;

  hipMemsetAsync(deg, 0, (size_t)N * 4, stream);
  hipMemsetAsync(counts, 0, (size_t)N * 4, stream);

  // CSR build
  k_edge_pass1<<<gE, TPB, 0, stream>>>(ei, ew, deg, counts, E);
  k_dinv<<<gN, TPB, 0, stream>>>(deg, dinv, N);
  k_scan1<<<gN, TPB, 0, stream>>>(counts, excl, bsum, N);
  k_scan2<<<1, TPB, 0, stream>>>(bsum, gN);
  k_scan3<<<gN, TPB, 0, stream>>>(excl, bsum, rp, wp, N, E);
  k_edge_pass2<<<gE, TPB, 0, stream>>>(ei, ew, dinv, wp, csrc, cnorm, E);

  // weight prep
  k_build_wt<<<60, TPB, 0, stream>>>(l1_Wx, l1_bx, l1_bh, l1_b, Wt1, be1);
  k_build_wt<<<60, TPB, 0, stream>>>(l2_Wx, l2_bx, l2_bh, l2_b, Wt2, be2);
  k_head_setup<<<1, 64, 0, stream>>>(hw1, hb1, hw2, hb2, hw3, hb3, hw4, hb4,
                                     weff);

  // layer 1 (T0 = x)
  k_prop<<<gP, TPB, 0, stream>>>(x, rp, csrc, cnorm, nullptr, 1.f, 0.f, T1, N);
  k_prop<<<gP, TPB, 0, stream>>>(T1, rp, csrc, cnorm, x, 2.f, -1.f, T2, N);
  k_prop<<<gP, TPB, 0, stream>>>(T2, rp, csrc, cnorm, T1, 2.f, -1.f, T3, N);
  k_prop<<<gP, TPB, 0, stream>>>(T3, rp, csrc, cnorm, T2, 2.f, -1.f, T4, N);
  k_gates<<<gG, 192, 0, stream>>>(x, T1, T2, T3, T4, Wt1, be1, l1_wc + 64, H1,
                                  N);

  // layer 2 (T0 = H1)
  k_prop<<<gP, TPB, 0, stream>>>(H1, rp, csrc, cnorm, nullptr, 1.f, 0.f, T1, N);
  k_prop<<<gP, TPB, 0, stream>>>(T1, rp, csrc, cnorm, H1, 2.f, -1.f, T2, N);
  k_prop<<<gP, TPB, 0, stream>>>(T2, rp, csrc, cnorm, T1, 2.f, -1.f, T3, N);
  k_prop<<<gP, TPB, 0, stream>>>(T3, rp, csrc, cnorm, T2, 2.f, -1.f, T4, N);
  k_gates<<<gG, 192, 0, stream>>>(H1, T1, T2, T3, T4, Wt2, be2, l2_wc + 64, H2,
                                  N);

  // head
  k_head<<<gN, TPB, 0, stream>>>(H2, weff, (float*)d_out, N);
}

// Round 2
// 847.993 us; speedup vs baseline: 1.3691x; 1.3691x over previous
//
#include <hip/hip_runtime.h>
#include <math.h>

// ---------------------------------------------------------------------------
// RecurrentGCN: 2x GConvLSTM(Cheb K=5) + ReLU + collapsed 4-linear head.
// Simplifications (H=C=0 at t=0): cheb(H=0)==bh (bias only); forget gate dead;
// head linears compose to single affine w_eff[32], b_eff.
// R1 changes: rank-from-atomic-return (pass2 atomic-free), packed 8B CSR
// (uint2 src+norm), wave-per-node prop with 2 edge-slots x 32 feats + unroll2
// (4 gathers in flight), dinv folded into scan3.
// ---------------------------------------------------------------------------

#define TPB 256

// ---- edge pass 1: deg histogram (by src) + counts histogram (by dst), -----
// ---- with the counts atomic's return value saved as the edge's rank. ------
__global__ __launch_bounds__(TPB) void k_edge_pass1(
    const int* __restrict__ ei, const float* __restrict__ ew,
    float* __restrict__ deg, int* __restrict__ counts, int* __restrict__ rank,
    int E) {
  int i = blockIdx.x * TPB + threadIdx.x;
  if (i >= E) return;
  int s = ei[i];
  int d = ei[E + i];
  atomicAdd(&deg[s], ew[i]);
  rank[i] = atomicAdd(&counts[d], 1);
}

// ---- 3-kernel exclusive scan of counts[n] ---------------------------------
__global__ __launch_bounds__(TPB) void k_scan1(
    const int* __restrict__ counts, int* __restrict__ excl,
    int* __restrict__ bsum, int n) {
  __shared__ int sh[TPB];
  int tid = threadIdx.x;
  int i = blockIdx.x * TPB + tid;
  int v = (i < n) ? counts[i] : 0;
  sh[tid] = v;
  __syncthreads();
  for (int off = 1; off < TPB; off <<= 1) {
    int t = (tid >= off) ? sh[tid - off] : 0;
    __syncthreads();
    sh[tid] += t;
    __syncthreads();
  }
  if (i < n) excl[i] = sh[tid] - v;
  if (tid == TPB - 1) bsum[blockIdx.x] = sh[TPB - 1];
}

__global__ __launch_bounds__(TPB) void k_scan2(int* __restrict__ bsum, int nb) {
  __shared__ int sh[TPB];
  int tid = threadIdx.x;
  int v = (tid < nb) ? bsum[tid] : 0;
  sh[tid] = v;
  __syncthreads();
  for (int off = 1; off < TPB; off <<= 1) {
    int t = (tid >= off) ? sh[tid - off] : 0;
    __syncthreads();
    sh[tid] += t;
    __syncthreads();
  }
  if (tid < nb) bsum[tid] = sh[tid] - v;
}

// ---- scan3 + dinv fold-in -------------------------------------------------
__global__ __launch_bounds__(TPB) void k_scan3(
    const int* __restrict__ excl, const int* __restrict__ bsum,
    const float* __restrict__ deg, int* __restrict__ rp,
    float* __restrict__ dinv, int n, int E) {
  int i = blockIdx.x * TPB + threadIdx.x;
  if (i < n) {
    rp[i] = excl[i] + bsum[i >> 8];
    float dg = deg[i];
    dinv[i] = (dg > 0.f) ? 1.0f / sqrtf(fmaxf(dg, 1e-12f)) : 0.f;
  }
  if (i == 0) rp[n] = E;
}

// ---- edge pass 2: atomic-free scatter of packed (src, norm) ---------------
__global__ __launch_bounds__(TPB) void k_edge_pass2(
    const int* __restrict__ ei, const float* __restrict__ ew,
    const float* __restrict__ dinv, const int* __restrict__ rp,
    const int* __restrict__ rank, uint2* __restrict__ epk, int E) {
  int i = blockIdx.x * TPB + threadIdx.x;
  if (i >= E) return;
  int s = ei[i];
  int d = ei[E + i];
  float nv = -dinv[s] * ew[i] * dinv[d];
  int pos = rp[d] + rank[i];
  uint2 p;
  p.x = (unsigned)s;
  p.y = __float_as_uint(nv);
  epk[pos] = p;
}

// ---- sparse prop: y[dst] = alpha * sum_e norm_e * x[src_e] + beta * prev --
// One node per wave64: 2 edge-slots x 32 features; unroll 2 -> 4 gathers
// in flight. Final shfl_xor(32) folds the edge slots.
__global__ __launch_bounds__(TPB) void k_prop(
    const float* __restrict__ xin, const int* __restrict__ rp,
    const uint2* __restrict__ epk, const float* __restrict__ prev,
    float alpha, float beta, float* __restrict__ yout, int n) {
  int tid = threadIdx.x;
  int node = blockIdx.x * 4 + (tid >> 6);
  if (node >= n) return;
  int lane = tid & 63;
  int es = lane >> 5;  // edge slot 0/1
  int f = lane & 31;
  int b = rp[node], e = rp[node + 1];
  float acc0 = 0.f, acc1 = 0.f;
  int t = b + es;
  for (; t + 2 < e; t += 4) {
    uint2 p0 = epk[t];
    uint2 p1 = epk[t + 2];
    acc0 = fmaf(__uint_as_float(p0.y), xin[(size_t)p0.x * 32 + f], acc0);
    acc1 = fmaf(__uint_as_float(p1.y), xin[(size_t)p1.x * 32 + f], acc1);
  }
  if (t < e) {
    uint2 p0 = epk[t];
    acc0 = fmaf(__uint_as_float(p0.y), xin[(size_t)p0.x * 32 + f], acc0);
  }
  float acc = acc0 + acc1;
  acc += __shfl_xor(acc, 32);
  if (es == 0) {
    float r = alpha * acc;
    if (prev != nullptr) r = fmaf(beta, prev[node * 32 + f], r);
    yout[node * 32 + f] = r;
  }
}

// ---- weight prep: Wt[k][j] (k=kk*32+i in 0..159, j=g3*32+h in 0..95) ------
// gates kept: g3=0 -> i (gate 0), g3=1 -> c (gate 2), g3=2 -> o (gate 3)
__global__ __launch_bounds__(TPB) void k_build_wt(
    const float* __restrict__ Wx, const float* __restrict__ bx,
    const float* __restrict__ bh, const float* __restrict__ bb,
    float* __restrict__ Wt, float* __restrict__ be) {
  int idx = blockIdx.x * TPB + threadIdx.x;
  if (idx < 160 * 96) {
    int k = idx / 96, j = idx % 96;
    int kk = k >> 5, i = k & 31;
    int g3 = j >> 5, h = j & 31;
    int g = (g3 == 0) ? 0 : (g3 == 1 ? 2 : 3);
    Wt[idx] = Wx[((g * 5 + kk) * 32 + i) * 32 + h];
  }
  if (idx < 96) {
    int g3 = idx >> 5, h = idx & 31;
    int g = (g3 == 0) ? 0 : (g3 == 1 ? 2 : 3);
    be[idx] = bx[g * 32 + h] + bh[g * 32 + h] + bb[g * 32 + h];
  }
}

// ---- head collapse: w_eff = hw1@hw2@hw3@hw4, b_eff similarly --------------
__global__ void k_head_setup(
    const float* __restrict__ hw1, const float* __restrict__ hb1,
    const float* __restrict__ hw2, const float* __restrict__ hb2,
    const float* __restrict__ hw3, const float* __restrict__ hb3,
    const float* __restrict__ hw4, const float* __restrict__ hb4,
    float* __restrict__ weff) {
  int a = threadIdx.x;
  if (a < 32) {
    float w12[8];
    for (int c = 0; c < 8; ++c) {
      float s = 0.f;
      for (int b = 0; b < 16; ++b) s += hw1[a * 16 + b] * hw2[b * 8 + c];
      w12[c] = s;
    }
    float w123[4];
    for (int d = 0; d < 4; ++d) {
      float s = 0.f;
      for (int c = 0; c < 8; ++c) s += w12[c] * hw3[c * 4 + d];
      w123[d] = s;
    }
    float s = 0.f;
    for (int d = 0; d < 4; ++d) s += w123[d] * hw4[d];
    weff[a] = s;
  }
  if (a == 32) {
    float t2[8];
    for (int c = 0; c < 8; ++c) {
      float s = hb2[c];
      for (int b = 0; b < 16; ++b) s += hb1[b] * hw2[b * 8 + c];
      t2[c] = s;
    }
    float t3[4];
    for (int d = 0; d < 4; ++d) {
      float s = hb3[d];
      for (int c = 0; c < 8; ++c) s += t2[c] * hw3[c * 4 + d];
      t3[d] = s;
    }
    float s = hb4[0];
    for (int d = 0; d < 4; ++d) s += t3[d] * hw4[d];
    weff[32] = s;
  }
}

// ---- fused gates: [50000 x 160] @ [160 x 96] + LSTM gate math + ReLU ------
// block: 192 threads, 32 nodes. thread owns (j = tid%96, node-group tid/96).
__global__ __launch_bounds__(192) void k_gates(
    const float* __restrict__ T0, const float* __restrict__ T1,
    const float* __restrict__ T2, const float* __restrict__ T3,
    const float* __restrict__ T4, const float* __restrict__ Wt,
    const float* __restrict__ be, const float* __restrict__ wc2,
    float* __restrict__ Hout, int n) {
  __shared__ float Tlds[32 * 164];   // 32 nodes x 160 cols, padded
  __shared__ float preLds[32 * 97];  // 32 nodes x 96 gate pre-acts, padded
  int tid = threadIdx.x;
  int base = blockIdx.x * 32;

  for (int idx = tid; idx < 5 * 1024; idx += 192) {
    int tsel = idx >> 10;
    int rem = idx & 1023;
    int node = rem >> 5, fi = rem & 31;
    int gn = base + node;
    const float* Tp = (tsel == 0) ? T0 : (tsel == 1) ? T1 : (tsel == 2) ? T2
                      : (tsel == 3) ? T3 : T4;
    Tlds[node * 164 + tsel * 32 + fi] = (gn < n) ? Tp[gn * 32 + fi] : 0.f;
  }
  __syncthreads();

  int j = tid % 96;
  int ng = tid / 96;
  float acc[16];
#pragma unroll
  for (int i = 0; i < 16; ++i) acc[i] = 0.f;

  for (int k4 = 0; k4 < 40; ++k4) {
    int k = k4 * 4;
    float w0 = Wt[(k + 0) * 96 + j];
    float w1 = Wt[(k + 1) * 96 + j];
    float w2 = Wt[(k + 2) * 96 + j];
    float w3 = Wt[(k + 3) * 96 + j];
#pragma unroll
    for (int i = 0; i < 16; ++i) {
      const float4 t =
          *reinterpret_cast<const float4*>(&Tlds[(ng * 16 + i) * 164 + k]);
      float a = acc[i];
      a = fmaf(t.x, w0, a);
      a = fmaf(t.y, w1, a);
      a = fmaf(t.z, w2, a);
      a = fmaf(t.w, w3, a);
      acc[i] = a;
    }
  }

  float bej = be[j];
#pragma unroll
  for (int i = 0; i < 16; ++i) preLds[(ng * 16 + i) * 97 + j] = acc[i] + bej;
  __syncthreads();

  for (int idx = tid; idx < 1024; idx += 192) {
    int node = idx >> 5, h = idx & 31;
    int gn = base + node;
    if (gn >= n) continue;
    float pi = preLds[node * 97 + h];
    float pc = preLds[node * 97 + 32 + h];
    float po = preLds[node * 97 + 64 + h];
    float I = 1.f / (1.f + expf(-pi));
    float Cn = I * tanhf(pc);
    float O = 1.f / (1.f + expf(-(po + wc2[h] * Cn)));
    Hout[gn * 32 + h] = fmaxf(O * tanhf(Cn), 0.f);
  }
}

// ---- head: out[n] = H2[n,:] . w_eff + b_eff -------------------------------
__global__ __launch_bounds__(TPB) void k_head(
    const float* __restrict__ H, const float* __restrict__ weff,
    float* __restrict__ out, int n) {
  int i = blockIdx.x * TPB + threadIdx.x;
  if (i >= n) return;
  const float4* hp = reinterpret_cast<const float4*>(H + i * 32);
  float s = weff[32];
#pragma unroll
  for (int q = 0; q < 8; ++q) {
    float4 v = hp[q];
    s = fmaf(v.x, weff[q * 4 + 0], s);
    s = fmaf(v.y, weff[q * 4 + 1], s);
    s = fmaf(v.z, weff[q * 4 + 2], s);
    s = fmaf(v.w, weff[q * 4 + 3], s);
  }
  out[i] = s;
}

extern "C" void kernel_launch(void* const* d_in, const int* in_sizes, int n_in,
                              void* d_out, int out_size, void* d_ws,
                              size_t ws_size, hipStream_t stream) {
  const float* x = (const float*)d_in[0];
  const int* ei = (const int*)d_in[1];
  const float* ew = (const float*)d_in[2];
  const float* l1_Wx = (const float*)d_in[3];
  const float* l1_bx = (const float*)d_in[4];
  const float* l1_bh = (const float*)d_in[6];
  const float* l1_wc = (const float*)d_in[7];
  const float* l1_b = (const float*)d_in[8];
  const float* l2_Wx = (const float*)d_in[9];
  const float* l2_bx = (const float*)d_in[10];
  const float* l2_bh = (const float*)d_in[12];
  const float* l2_wc = (const float*)d_in[13];
  const float* l2_b = (const float*)d_in[14];
  const float* hw1 = (const float*)d_in[15];
  const float* hb1 = (const float*)d_in[16];
  const float* hw2 = (const float*)d_in[17];
  const float* hb2 = (const float*)d_in[18];
  const float* hw3 = (const float*)d_in[19];
  const float* hb3 = (const float*)d_in[20];
  const float* hw4 = (const float*)d_in[21];
  const float* hb4 = (const float*)d_in[22];

  const int N = in_sizes[0] / 32;
  const int E = in_sizes[1] / 2;

  // workspace carve-out (256B aligned)
  char* w = (char*)d_ws;
  auto alloc = [&](size_t bytes) -> void* {
    void* p = (void*)w;
    w += (bytes + 255) & ~(size_t)255;
    return p;
  };
  float* deg = (float*)alloc((size_t)N * 4);
  int* counts = (int*)alloc((size_t)N * 4);
  float* dinv = (float*)alloc((size_t)N * 4);
  int* rp = (int*)alloc((size_t)(N + 1) * 4);
  int* excl = (int*)alloc((size_t)N * 4);
  int* bsum = (int*)alloc(256 * 4);
  int* rank = (int*)alloc((size_t)E * 4);
  uint2* epk = (uint2*)alloc((size_t)E * 8);
  float* T1 = (float*)alloc((size_t)N * 32 * 4);
  float* T2 = (float*)alloc((size_t)N * 32 * 4);
  float* T3 = (float*)alloc((size_t)N * 32 * 4);
  float* T4 = (float*)alloc((size_t)N * 32 * 4);
  float* H1 = (float*)alloc((size_t)N * 32 * 4);
  float* H2 = (float*)alloc((size_t)N * 32 * 4);
  float* Wt1 = (float*)alloc(160 * 96 * 4);
  float* be1 = (float*)alloc(96 * 4);
  float* Wt2 = (float*)alloc(160 * 96 * 4);
  float* be2 = (float*)alloc(96 * 4);
  float* weff = (float*)alloc(40 * 4);

  const int gE = (E + TPB - 1) / TPB;
  const int gN = (N + TPB - 1) / TPB;
  const int gP = (N + 3) / 4;
  const int gG = (N + 31) / 32;

  hipMemsetAsync(deg, 0, (size_t)N * 4, stream);
  hipMemsetAsync(counts, 0, (size_t)N * 4, stream);

  // CSR build
  k_edge_pass1<<<gE, TPB, 0, stream>>>(ei, ew, deg, counts, rank, E);
  k_scan1<<<gN, TPB, 0, stream>>>(counts, excl, bsum, N);
  k_scan2<<<1, TPB, 0, stream>>>(bsum, gN);
  k_scan3<<<gN, TPB, 0, stream>>>(excl, bsum, deg, rp, dinv, N, E);
  k_edge_pass2<<<gE, TPB, 0, stream>>>(ei, ew, dinv, rp, rank, epk, E);

  // weight prep
  k_build_wt<<<60, TPB, 0, stream>>>(l1_Wx, l1_bx, l1_bh, l1_b, Wt1, be1);
  k_build_wt<<<60, TPB, 0, stream>>>(l2_Wx, l2_bx, l2_bh, l2_b, Wt2, be2);
  k_head_setup<<<1, 64, 0, stream>>>(hw1, hb1, hw2, hb2, hw3, hb3, hw4, hb4,
                                     weff);

  // layer 1 (T0 = x)
  k_prop<<<gP, TPB, 0, stream>>>(x, rp, epk, nullptr, 1.f, 0.f, T1, N);
  k_prop<<<gP, TPB, 0, stream>>>(T1, rp, epk, x, 2.f, -1.f, T2, N);
  k_prop<<<gP, TPB, 0, stream>>>(T2, rp, epk, T1, 2.f, -1.f, T3, N);
  k_prop<<<gP, TPB, 0, stream>>>(T3, rp, epk, T2, 2.f, -1.f, T4, N);
  k_gates<<<gG, 192, 0, stream>>>(x, T1, T2, T3, T4, Wt1, be1, l1_wc + 64, H1,
                                  N);

  // layer 2 (T0 = H1)
  k_prop<<<gP, TPB, 0, stream>>>(H1, rp, epk, nullptr, 1.f, 0.f, T1, N);
  k_prop<<<gP, TPB, 0, stream>>>(T1, rp, epk, H1, 2.f, -1.f, T2, N);
  k_prop<<<gP, TPB, 0, stream>>>(T2, rp, epk, T1, 2.f, -1.f, T3, N);
  k_prop<<<gP, TPB, 0, stream>>>(T3, rp, epk, T2, 2.f, -1.f, T4, N);
  k_gates<<<gG, 192, 0, stream>>>(H1, T1, T2, T3, T4, Wt2, be2, l2_wc + 64, H2,
                                  N);

  // head
  k_head<<<gN, TPB, 0, stream>>>(H2, weff, (float*)d_out, N);
}

// Round 3
// 753.878 us; speedup vs baseline: 1.5400x; 1.1248x over previous
//
#include <hip/hip_runtime.h>
#include <math.h>

// ---------------------------------------------------------------------------
// RecurrentGCN: 2x GConvLSTM(Cheb K=5) + ReLU + collapsed 4-linear head.
// Simplifications (H=C=0 at t=0): cheb(H=0)==bh (bias only); forget gate dead;
// head linears compose to single affine w_eff[32], b_eff.
// R2 changes: per-XCD histograms with L2-local (workgroup-scope) atomics
// (device-scope atomics were doing 32B memory-side write-through = 105MB),
// fixed-point integer degree accumulation, off8 per-(xcd,dst) bases folded
// into scan3, prop unrolled 4x (8 gather chains in flight per wave).
// ---------------------------------------------------------------------------

#define TPB 256
#define NX 8                    // XCDs on MI355X
#define DEG_SCALE 16777216.0f   // 2^24 fixed-point for degree accumulation

__device__ __forceinline__ int xcc_id() {
  int x;
  asm volatile("s_getreg_b32 %0, hwreg(HW_REG_XCC_ID)" : "=s"(x));
  return x & (NX - 1);
}

// ---- edge pass 1: per-XCD deg histogram (by src) + count histogram (by ----
// ---- dst) using L2-local atomics; count's return value is the local rank. -
__global__ __launch_bounds__(TPB) void k_edge_pass1(
    const int* __restrict__ ei, const float* __restrict__ ew,
    int* __restrict__ degi, int* __restrict__ cnti, int* __restrict__ rank,
    int N, int E) {
  int i = blockIdx.x * TPB + threadIdx.x;
  if (i >= E) return;
  int x = xcc_id();
  int s = ei[i];
  int d = ei[E + i];
  int dv = (int)(ew[i] * DEG_SCALE + 0.5f);
  __hip_atomic_fetch_add(&degi[x * N + s], dv, __ATOMIC_RELAXED,
                         __HIP_MEMORY_SCOPE_WORKGROUP);
  int lr = __hip_atomic_fetch_add(&cnti[x * N + d], 1, __ATOMIC_RELAXED,
                                  __HIP_MEMORY_SCOPE_WORKGROUP);
  rank[i] = (x << 27) | lr;
}

// ---- 3-kernel exclusive scan of total counts[n] ---------------------------
__global__ __launch_bounds__(TPB) void k_scan1(
    const int* __restrict__ cnti, int* __restrict__ excl,
    int* __restrict__ bsum, int n) {
  __shared__ int sh[TPB];
  int tid = threadIdx.x;
  int i = blockIdx.x * TPB + tid;
  int v = 0;
  if (i < n) {
#pragma unroll
    for (int x = 0; x < NX; ++x) v += cnti[x * n + i];
  }
  sh[tid] = v;
  __syncthreads();
  for (int off = 1; off < TPB; off <<= 1) {
    int t = (tid >= off) ? sh[tid - off] : 0;
    __syncthreads();
    sh[tid] += t;
    __syncthreads();
  }
  if (i < n) excl[i] = sh[tid] - v;
  if (tid == TPB - 1) bsum[blockIdx.x] = sh[TPB - 1];
}

__global__ __launch_bounds__(TPB) void k_scan2(int* __restrict__ bsum, int nb) {
  __shared__ int sh[TPB];
  int tid = threadIdx.x;
  int v = (tid < nb) ? bsum[tid] : 0;
  sh[tid] = v;
  __syncthreads();
  for (int off = 1; off < TPB; off <<= 1) {
    int t = (tid >= off) ? sh[tid - off] : 0;
    __syncthreads();
    sh[tid] += t;
    __syncthreads();
  }
  if (tid < nb) bsum[tid] = sh[tid] - v;
}

// ---- scan3: rp + per-(xcd,dst) bases (off8) + dinv ------------------------
__global__ __launch_bounds__(TPB) void k_scan3(
    const int* __restrict__ excl, const int* __restrict__ bsum,
    const int* __restrict__ degi, const int* __restrict__ cnti,
    int* __restrict__ rp, int* __restrict__ off8, float* __restrict__ dinv,
    int n, int E) {
  int i = blockIdx.x * TPB + threadIdx.x;
  if (i < n) {
    int r = excl[i] + bsum[i >> 8];
    rp[i] = r;
    int run = r;
#pragma unroll
    for (int x = 0; x < NX; ++x) {
      off8[x * n + i] = run;
      run += cnti[x * n + i];
    }
    int ds = 0;
#pragma unroll
    for (int x = 0; x < NX; ++x) ds += degi[x * n + i];
    float dg = (float)ds * (1.0f / DEG_SCALE);
    dinv[i] = (ds > 0) ? 1.0f / sqrtf(fmaxf(dg, 1e-12f)) : 0.f;
  }
  if (i == 0) rp[n] = E;
}

// ---- edge pass 2: atomic-free scatter of packed (src, norm) ---------------
__global__ __launch_bounds__(TPB) void k_edge_pass2(
    const int* __restrict__ ei, const float* __restrict__ ew,
    const float* __restrict__ dinv, const int* __restrict__ off8,
    const int* __restrict__ rank, uint2* __restrict__ epk, int N, int E) {
  int i = blockIdx.x * TPB + threadIdx.x;
  if (i >= E) return;
  int s = ei[i];
  int d = ei[E + i];
  float nv = -dinv[s] * ew[i] * dinv[d];
  int rk = rank[i];
  int x = rk >> 27;
  int lr = rk & 0x7FFFFFF;
  int pos = off8[x * N + d] + lr;
  uint2 p;
  p.x = (unsigned)s;
  p.y = __float_as_uint(nv);
  epk[pos] = p;
}

// ---- sparse prop: y[dst] = alpha * sum_e norm_e * x[src_e] + beta * prev --
// One node per wave64: 2 edge-slots x 32 features, unroll 4 -> 8 independent
// gather chains in flight per wave. Final shfl_xor(32) folds the edge slots.
__global__ __launch_bounds__(TPB) void k_prop(
    const float* __restrict__ xin, const int* __restrict__ rp,
    const uint2* __restrict__ epk, const float* __restrict__ prev,
    float alpha, float beta, float* __restrict__ yout, int n) {
  int tid = threadIdx.x;
  int node = blockIdx.x * 4 + (tid >> 6);
  if (node >= n) return;
  int lane = tid & 63;
  int es = lane >> 5;  // edge slot 0/1
  int f = lane & 31;
  int b = rp[node], e = rp[node + 1];
  float acc0 = 0.f, acc1 = 0.f, acc2 = 0.f, acc3 = 0.f;
  int t = b + es;
  for (; t + 6 < e; t += 8) {
    uint2 p0 = epk[t];
    uint2 p1 = epk[t + 2];
    uint2 p2 = epk[t + 4];
    uint2 p3 = epk[t + 6];
    acc0 = fmaf(__uint_as_float(p0.y), xin[(size_t)p0.x * 32 + f], acc0);
    acc1 = fmaf(__uint_as_float(p1.y), xin[(size_t)p1.x * 32 + f], acc1);
    acc2 = fmaf(__uint_as_float(p2.y), xin[(size_t)p2.x * 32 + f], acc2);
    acc3 = fmaf(__uint_as_float(p3.y), xin[(size_t)p3.x * 32 + f], acc3);
  }
  for (; t < e; t += 2) {
    uint2 p0 = epk[t];
    acc0 = fmaf(__uint_as_float(p0.y), xin[(size_t)p0.x * 32 + f], acc0);
  }
  float acc = (acc0 + acc2) + (acc1 + acc3);
  acc += __shfl_xor(acc, 32);
  if (es == 0) {
    float r = alpha * acc;
    if (prev != nullptr) r = fmaf(beta, prev[node * 32 + f], r);
    yout[node * 32 + f] = r;
  }
}

// ---- weight prep: Wt[k][j] (k=kk*32+i in 0..159, j=g3*32+h in 0..95) ------
// gates kept: g3=0 -> i (gate 0), g3=1 -> c (gate 2), g3=2 -> o (gate 3)
__global__ __launch_bounds__(TPB) void k_build_wt(
    const float* __restrict__ Wx, const float* __restrict__ bx,
    const float* __restrict__ bh, const float* __restrict__ bb,
    float* __restrict__ Wt, float* __restrict__ be) {
  int idx = blockIdx.x * TPB + threadIdx.x;
  if (idx < 160 * 96) {
    int k = idx / 96, j = idx % 96;
    int kk = k >> 5, i = k & 31;
    int g3 = j >> 5, h = j & 31;
    int g = (g3 == 0) ? 0 : (g3 == 1 ? 2 : 3);
    Wt[idx] = Wx[((g * 5 + kk) * 32 + i) * 32 + h];
  }
  if (idx < 96) {
    int g3 = idx >> 5, h = idx & 31;
    int g = (g3 == 0) ? 0 : (g3 == 1 ? 2 : 3);
    be[idx] = bx[g * 32 + h] + bh[g * 32 + h] + bb[g * 32 + h];
  }
}

// ---- head collapse: w_eff = hw1@hw2@hw3@hw4, b_eff similarly --------------
__global__ void k_head_setup(
    const float* __restrict__ hw1, const float* __restrict__ hb1,
    const float* __restrict__ hw2, const float* __restrict__ hb2,
    const float* __restrict__ hw3, const float* __restrict__ hb3,
    const float* __restrict__ hw4, const float* __restrict__ hb4,
    float* __restrict__ weff) {
  int a = threadIdx.x;
  if (a < 32) {
    float w12[8];
    for (int c = 0; c < 8; ++c) {
      float s = 0.f;
      for (int b = 0; b < 16; ++b) s += hw1[a * 16 + b] * hw2[b * 8 + c];
      w12[c] = s;
    }
    float w123[4];
    for (int d = 0; d < 4; ++d) {
      float s = 0.f;
      for (int c = 0; c < 8; ++c) s += w12[c] * hw3[c * 4 + d];
      w123[d] = s;
    }
    float s = 0.f;
    for (int d = 0; d < 4; ++d) s += w123[d] * hw4[d];
    weff[a] = s;
  }
  if (a == 32) {
    float t2[8];
    for (int c = 0; c < 8; ++c) {
      float s = hb2[c];
      for (int b = 0; b < 16; ++b) s += hb1[b] * hw2[b * 8 + c];
      t2[c] = s;
    }
    float t3[4];
    for (int d = 0; d < 4; ++d) {
      float s = hb3[d];
      for (int c = 0; c < 8; ++c) s += t2[c] * hw3[c * 4 + d];
      t3[d] = s;
    }
    float s = hb4[0];
    for (int d = 0; d < 4; ++d) s += t3[d] * hw4[d];
    weff[32] = s;
  }
}

// ---- fused gates: [50000 x 160] @ [160 x 96] + LSTM gate math + ReLU ------
// block: 192 threads, 32 nodes. thread owns (j = tid%96, node-group tid/96).
__global__ __launch_bounds__(192) void k_gates(
    const float* __restrict__ T0, const float* __restrict__ T1,
    const float* __restrict__ T2, const float* __restrict__ T3,
    const float* __restrict__ T4, const float* __restrict__ Wt,
    const float* __restrict__ be, const float* __restrict__ wc2,
    float* __restrict__ Hout, int n) {
  __shared__ float Tlds[32 * 164];   // 32 nodes x 160 cols, padded
  __shared__ float preLds[32 * 97];  // 32 nodes x 96 gate pre-acts, padded
  int tid = threadIdx.x;
  int base = blockIdx.x * 32;

  for (int idx = tid; idx < 5 * 1024; idx += 192) {
    int tsel = idx >> 10;
    int rem = idx & 1023;
    int node = rem >> 5, fi = rem & 31;
    int gn = base + node;
    const float* Tp = (tsel == 0) ? T0 : (tsel == 1) ? T1 : (tsel == 2) ? T2
                      : (tsel == 3) ? T3 : T4;
    Tlds[node * 164 + tsel * 32 + fi] = (gn < n) ? Tp[gn * 32 + fi] : 0.f;
  }
  __syncthreads();

  int j = tid % 96;
  int ng = tid / 96;
  float acc[16];
#pragma unroll
  for (int i = 0; i < 16; ++i) acc[i] = 0.f;

  for (int k4 = 0; k4 < 40; ++k4) {
    int k = k4 * 4;
    float w0 = Wt[(k + 0) * 96 + j];
    float w1 = Wt[(k + 1) * 96 + j];
    float w2 = Wt[(k + 2) * 96 + j];
    float w3 = Wt[(k + 3) * 96 + j];
#pragma unroll
    for (int i = 0; i < 16; ++i) {
      const float4 t =
          *reinterpret_cast<const float4*>(&Tlds[(ng * 16 + i) * 164 + k]);
      float a = acc[i];
      a = fmaf(t.x, w0, a);
      a = fmaf(t.y, w1, a);
      a = fmaf(t.z, w2, a);
      a = fmaf(t.w, w3, a);
      acc[i] = a;
    }
  }

  float bej = be[j];
#pragma unroll
  for (int i = 0; i < 16; ++i) preLds[(ng * 16 + i) * 97 + j] = acc[i] + bej;
  __syncthreads();

  for (int idx = tid; idx < 1024; idx += 192) {
    int node = idx >> 5, h = idx & 31;
    int gn = base + node;
    if (gn >= n) continue;
    float pi = preLds[node * 97 + h];
    float pc = preLds[node * 97 + 32 + h];
    float po = preLds[node * 97 + 64 + h];
    float I = 1.f / (1.f + expf(-pi));
    float Cn = I * tanhf(pc);
    float O = 1.f / (1.f + expf(-(po + wc2[h] * Cn)));
    Hout[gn * 32 + h] = fmaxf(O * tanhf(Cn), 0.f);
  }
}

// ---- head: out[n] = H2[n,:] . w_eff + b_eff -------------------------------
__global__ __launch_bounds__(TPB) void k_head(
    const float* __restrict__ H, const float* __restrict__ weff,
    float* __restrict__ out, int n) {
  int i = blockIdx.x * TPB + threadIdx.x;
  if (i >= n) return;
  const float4* hp = reinterpret_cast<const float4*>(H + i * 32);
  float s = weff[32];
#pragma unroll
  for (int q = 0; q < 8; ++q) {
    float4 v = hp[q];
    s = fmaf(v.x, weff[q * 4 + 0], s);
    s = fmaf(v.y, weff[q * 4 + 1], s);
    s = fmaf(v.z, weff[q * 4 + 2], s);
    s = fmaf(v.w, weff[q * 4 + 3], s);
  }
  out[i] = s;
}

extern "C" void kernel_launch(void* const* d_in, const int* in_sizes, int n_in,
                              void* d_out, int out_size, void* d_ws,
                              size_t ws_size, hipStream_t stream) {
  const float* x = (const float*)d_in[0];
  const int* ei = (const int*)d_in[1];
  const float* ew = (const float*)d_in[2];
  const float* l1_Wx = (const float*)d_in[3];
  const float* l1_bx = (const float*)d_in[4];
  const float* l1_bh = (const float*)d_in[6];
  const float* l1_wc = (const float*)d_in[7];
  const float* l1_b = (const float*)d_in[8];
  const float* l2_Wx = (const float*)d_in[9];
  const float* l2_bx = (const float*)d_in[10];
  const float* l2_bh = (const float*)d_in[12];
  const float* l2_wc = (const float*)d_in[13];
  const float* l2_b = (const float*)d_in[14];
  const float* hw1 = (const float*)d_in[15];
  const float* hb1 = (const float*)d_in[16];
  const float* hw2 = (const float*)d_in[17];
  const float* hb2 = (const float*)d_in[18];
  const float* hw3 = (const float*)d_in[19];
  const float* hb3 = (const float*)d_in[20];
  const float* hw4 = (const float*)d_in[21];
  const float* hb4 = (const float*)d_in[22];

  const int N = in_sizes[0] / 32;
  const int E = in_sizes[1] / 2;

  // workspace carve-out (256B aligned)
  char* w = (char*)d_ws;
  auto alloc = [&](size_t bytes) -> void* {
    void* p = (void*)w;
    w += (bytes + 255) & ~(size_t)255;
    return p;
  };
  int* degi = (int*)alloc((size_t)NX * N * 4);   // contiguous with cnti for
  int* cnti = (int*)alloc((size_t)NX * N * 4);   // a single memset
  int* off8 = (int*)alloc((size_t)NX * N * 4);
  float* dinv = (float*)alloc((size_t)N * 4);
  int* rp = (int*)alloc((size_t)(N + 1) * 4);
  int* excl = (int*)alloc((size_t)N * 4);
  int* bsum = (int*)alloc(256 * 4);
  int* rank = (int*)alloc((size_t)E * 4);
  uint2* epk = (uint2*)alloc((size_t)E * 8);
  float* T1 = (float*)alloc((size_t)N * 32 * 4);
  float* T2 = (float*)alloc((size_t)N * 32 * 4);
  float* T3 = (float*)alloc((size_t)N * 32 * 4);
  float* T4 = (float*)alloc((size_t)N * 32 * 4);
  float* H1 = (float*)alloc((size_t)N * 32 * 4);
  float* H2 = (float*)alloc((size_t)N * 32 * 4);
  float* Wt1 = (float*)alloc(160 * 96 * 4);
  float* be1 = (float*)alloc(96 * 4);
  float* Wt2 = (float*)alloc(160 * 96 * 4);
  float* be2 = (float*)alloc(96 * 4);
  float* weff = (float*)alloc(40 * 4);

  const int gE = (E + TPB - 1) / TPB;
  const int gN = (N + TPB - 1) / TPB;
  const int gP = (N + 3) / 4;
  const int gG = (N + 31) / 32;

  hipMemsetAsync(degi, 0, (size_t)2 * NX * N * 4, stream);  // degi + cnti

  // CSR build
  k_edge_pass1<<<gE, TPB, 0, stream>>>(ei, ew, degi, cnti, rank, N, E);
  k_scan1<<<gN, TPB, 0, stream>>>(cnti, excl, bsum, N);
  k_scan2<<<1, TPB, 0, stream>>>(bsum, gN);
  k_scan3<<<gN, TPB, 0, stream>>>(excl, bsum, degi, cnti, rp, off8, dinv, N,
                                  E);
  k_edge_pass2<<<gE, TPB, 0, stream>>>(ei, ew, dinv, off8, rank, epk, N, E);

  // weight prep
  k_build_wt<<<60, TPB, 0, stream>>>(l1_Wx, l1_bx, l1_bh, l1_b, Wt1, be1);
  k_build_wt<<<60, TPB, 0, stream>>>(l2_Wx, l2_bx, l2_bh, l2_b, Wt2, be2);
  k_head_setup<<<1, 64, 0, stream>>>(hw1, hb1, hw2, hb2, hw3, hb3, hw4, hb4,
                                     weff);

  // layer 1 (T0 = x)
  k_prop<<<gP, TPB, 0, stream>>>(x, rp, epk, nullptr, 1.f, 0.f, T1, N);
  k_prop<<<gP, TPB, 0, stream>>>(T1, rp, epk, x, 2.f, -1.f, T2, N);
  k_prop<<<gP, TPB, 0, stream>>>(T2, rp, epk, T1, 2.f, -1.f, T3, N);
  k_prop<<<gP, TPB, 0, stream>>>(T3, rp, epk, T2, 2.f, -1.f, T4, N);
  k_gates<<<gG, 192, 0, stream>>>(x, T1, T2, T3, T4, Wt1, be1, l1_wc + 64, H1,
                                  N);

  // layer 2 (T0 = H1)
  k_prop<<<gP, TPB, 0, stream>>>(H1, rp, epk, nullptr, 1.f, 0.f, T1, N);
  k_prop<<<gP, TPB, 0, stream>>>(T1, rp, epk, H1, 2.f, -1.f, T2, N);
  k_prop<<<gP, TPB, 0, stream>>>(T2, rp, epk, T1, 2.f, -1.f, T3, N);
  k_prop<<<gP, TPB, 0, stream>>>(T3, rp, epk, T2, 2.f, -1.f, T4, N);
  k_gates<<<gG, 192, 0, stream>>>(H1, T1, T2, T3, T4, Wt2, be2, l2_wc + 64, H2,
                                  N);

  // head
  k_head<<<gN, TPB, 0, stream>>>(H2, weff, (float*)d_out, N);
}

// Round 4
// 639.946 us; speedup vs baseline: 1.8142x; 1.1780x over previous
//
#include <hip/hip_runtime.h>
#include <math.h>

// ---------------------------------------------------------------------------
// RecurrentGCN: 2x GConvLSTM(Cheb K=5) + ReLU + collapsed 4-linear head.
// Simplifications (H=C=0 at t=0): cheb(H=0)==bh (bias only); forget gate dead;
// head linears compose to single affine w_eff[32], b_eff.
// R3 changes: prop reworked to 8 edge-slots x float4-features per wave
// (1 gather instr per 8 edges, 16 edges in flight/wave), CSR padded to
// multiple-of-16 segments (branch-free unroll-2 loop, zero pads), rank
// overlaid on T1 to keep workspace flat. CSR-build atomics unchanged
// (R2 post-mortem: scope hints don't change memory-side atomic execution).
// ---------------------------------------------------------------------------

#define TPB 256
#define NX 8                    // XCDs on MI355X
#define DEG_SCALE 16777216.0f   // 2^24 fixed-point for degree accumulation
#define PADM 15                 // segment pad: round up to multiple of 16

__device__ __forceinline__ int xcc_id() {
  int x;
  asm volatile("s_getreg_b32 %0, hwreg(HW_REG_XCC_ID)" : "=s"(x));
  return x & (NX - 1);
}

// ---- edge pass 1: per-XCD deg histogram (by src) + count histogram (by ----
// ---- dst); count's return value is the local rank. ------------------------
__global__ __launch_bounds__(TPB) void k_edge_pass1(
    const int* __restrict__ ei, const float* __restrict__ ew,
    int* __restrict__ degi, int* __restrict__ cnti, int* __restrict__ rank,
    int N, int E) {
  int i = blockIdx.x * TPB + threadIdx.x;
  if (i >= E) return;
  int x = xcc_id();
  int s = ei[i];
  int d = ei[E + i];
  int dv = (int)(ew[i] * DEG_SCALE + 0.5f);
  __hip_atomic_fetch_add(&degi[x * N + s], dv, __ATOMIC_RELAXED,
                         __HIP_MEMORY_SCOPE_WORKGROUP);
  int lr = __hip_atomic_fetch_add(&cnti[x * N + d], 1, __ATOMIC_RELAXED,
                                  __HIP_MEMORY_SCOPE_WORKGROUP);
  rank[i] = (x << 27) | lr;
}

// ---- 3-kernel exclusive scan of PADDED totals ----------------------------
__global__ __launch_bounds__(TPB) void k_scan1(
    const int* __restrict__ cnti, int* __restrict__ excl,
    int* __restrict__ bsum, int n) {
  __shared__ int sh[TPB];
  int tid = threadIdx.x;
  int i = blockIdx.x * TPB + tid;
  int v = 0;
  if (i < n) {
#pragma unroll
    for (int x = 0; x < NX; ++x) v += cnti[x * n + i];
    v = (v + PADM) & ~PADM;
  }
  sh[tid] = v;
  __syncthreads();
  for (int off = 1; off < TPB; off <<= 1) {
    int t = (tid >= off) ? sh[tid - off] : 0;
    __syncthreads();
    sh[tid] += t;
    __syncthreads();
  }
  if (i < n) excl[i] = sh[tid] - v;
  if (tid == TPB - 1) bsum[blockIdx.x] = sh[TPB - 1];
}

__global__ __launch_bounds__(TPB) void k_scan2(int* __restrict__ bsum, int nb) {
  __shared__ int sh[TPB];
  int tid = threadIdx.x;
  int v = (tid < nb) ? bsum[tid] : 0;
  sh[tid] = v;
  __syncthreads();
  for (int off = 1; off < TPB; off <<= 1) {
    int t = (tid >= off) ? sh[tid - off] : 0;
    __syncthreads();
    sh[tid] += t;
    __syncthreads();
  }
  if (tid < nb) bsum[tid] = sh[tid] - v;
}

// ---- scan3: padded rp + per-(xcd,dst) bases (off8) + dinv -----------------
__global__ __launch_bounds__(TPB) void k_scan3(
    const int* __restrict__ excl, const int* __restrict__ bsum,
    const int* __restrict__ degi, const int* __restrict__ cnti,
    int* __restrict__ rp, int* __restrict__ off8, float* __restrict__ dinv,
    int n) {
  int i = blockIdx.x * TPB + threadIdx.x;
  if (i < n) {
    int r = excl[i] + bsum[i >> 8];
    rp[i] = r;
    int run = r;
#pragma unroll
    for (int x = 0; x < NX; ++x) {
      off8[x * n + i] = run;
      run += cnti[x * n + i];
    }
    int raw = run - r;
    if (i == n - 1) rp[n] = r + ((raw + PADM) & ~PADM);
    int ds = 0;
#pragma unroll
    for (int x = 0; x < NX; ++x) ds += degi[x * n + i];
    float dg = (float)ds * (1.0f / DEG_SCALE);
    dinv[i] = (ds > 0) ? 1.0f / sqrtf(fmaxf(dg, 1e-12f)) : 0.f;
  }
}

// ---- edge pass 2: atomic-free scatter of packed (src, norm) ---------------
__global__ __launch_bounds__(TPB) void k_edge_pass2(
    const int* __restrict__ ei, const float* __restrict__ ew,
    const float* __restrict__ dinv, const int* __restrict__ off8,
    const int* __restrict__ rank, uint2* __restrict__ epk, int N, int E) {
  int i = blockIdx.x * TPB + threadIdx.x;
  if (i >= E) return;
  int s = ei[i];
  int d = ei[E + i];
  float nv = -dinv[s] * ew[i] * dinv[d];
  int rk = rank[i];
  int x = rk >> 27;
  int lr = rk & 0x7FFFFFF;
  int pos = off8[x * N + d] + lr;
  uint2 p;
  p.x = (unsigned)s;
  p.y = __float_as_uint(nv);
  epk[pos] = p;
}

// ---- sparse prop: y[dst] = alpha * sum_e norm_e * x[src_e] + beta * prev --
// One node per wave64: 8 edge-slots x 8 feature-quad lanes (float4).
// Padded CSR (x16, zero pads) -> branch-free unroll-2: 16 edges in flight.
__global__ __launch_bounds__(TPB) void k_prop(
    const float* __restrict__ xin, const int* __restrict__ rp,
    const uint2* __restrict__ epk, const float* __restrict__ prev,
    float alpha, float beta, float* __restrict__ yout, int n) {
  int tid = threadIdx.x;
  int node = blockIdx.x * 4 + (tid >> 6);
  if (node >= n) return;
  int lane = tid & 63;
  int slot = lane >> 3;  // 0..7 edge slot
  int fq = lane & 7;     // feature quad: features [4fq, 4fq+4)
  int b = rp[node], e = rp[node + 1];
  float4 a0 = make_float4(0.f, 0.f, 0.f, 0.f);
  float4 a1 = a0;
  for (int t = b + slot; t < e; t += 16) {
    uint2 p0 = epk[t];
    uint2 p1 = epk[t + 8];
    const float4 x0 =
        *reinterpret_cast<const float4*>(&xin[(size_t)p0.x * 32 + (fq << 2)]);
    const float4 x1 =
        *reinterpret_cast<const float4*>(&xin[(size_t)p1.x * 32 + (fq << 2)]);
    float n0 = __uint_as_float(p0.y);
    float n1 = __uint_as_float(p1.y);
    a0.x = fmaf(n0, x0.x, a0.x);
    a0.y = fmaf(n0, x0.y, a0.y);
    a0.z = fmaf(n0, x0.z, a0.z);
    a0.w = fmaf(n0, x0.w, a0.w);
    a1.x = fmaf(n1, x1.x, a1.x);
    a1.y = fmaf(n1, x1.y, a1.y);
    a1.z = fmaf(n1, x1.z, a1.z);
    a1.w = fmaf(n1, x1.w, a1.w);
  }
  float4 acc;
  acc.x = a0.x + a1.x;
  acc.y = a0.y + a1.y;
  acc.z = a0.z + a1.z;
  acc.w = a0.w + a1.w;
#pragma unroll
  for (int m = 8; m <= 32; m <<= 1) {
    acc.x += __shfl_xor(acc.x, m);
    acc.y += __shfl_xor(acc.y, m);
    acc.z += __shfl_xor(acc.z, m);
    acc.w += __shfl_xor(acc.w, m);
  }
  if (slot == 0) {
    float4 r;
    r.x = alpha * acc.x;
    r.y = alpha * acc.y;
    r.z = alpha * acc.z;
    r.w = alpha * acc.w;
    if (prev != nullptr) {
      const float4 pv = *reinterpret_cast<const float4*>(
          &prev[(size_t)node * 32 + (fq << 2)]);
      r.x = fmaf(beta, pv.x, r.x);
      r.y = fmaf(beta, pv.y, r.y);
      r.z = fmaf(beta, pv.z, r.z);
      r.w = fmaf(beta, pv.w, r.w);
    }
    *reinterpret_cast<float4*>(&yout[(size_t)node * 32 + (fq << 2)]) = r;
  }
}

// ---- weight prep: Wt[k][j] (k=kk*32+i in 0..159, j=g3*32+h in 0..95) ------
// gates kept: g3=0 -> i (gate 0), g3=1 -> c (gate 2), g3=2 -> o (gate 3)
__global__ __launch_bounds__(TPB) void k_build_wt(
    const float* __restrict__ Wx, const float* __restrict__ bx,
    const float* __restrict__ bh, const float* __restrict__ bb,
    float* __restrict__ Wt, float* __restrict__ be) {
  int idx = blockIdx.x * TPB + threadIdx.x;
  if (idx < 160 * 96) {
    int k = idx / 96, j = idx % 96;
    int kk = k >> 5, i = k & 31;
    int g3 = j >> 5, h = j & 31;
    int g = (g3 == 0) ? 0 : (g3 == 1 ? 2 : 3);
    Wt[idx] = Wx[((g * 5 + kk) * 32 + i) * 32 + h];
  }
  if (idx < 96) {
    int g3 = idx >> 5, h = idx & 31;
    int g = (g3 == 0) ? 0 : (g3 == 1 ? 2 : 3);
    be[idx] = bx[g * 32 + h] + bh[g * 32 + h] + bb[g * 32 + h];
  }
}

// ---- head collapse: w_eff = hw1@hw2@hw3@hw4, b_eff similarly --------------
__global__ void k_head_setup(
    const float* __restrict__ hw1, const float* __restrict__ hb1,
    const float* __restrict__ hw2, const float* __restrict__ hb2,
    const float* __restrict__ hw3, const float* __restrict__ hb3,
    const float* __restrict__ hw4, const float* __restrict__ hb4,
    float* __restrict__ weff) {
  int a = threadIdx.x;
  if (a < 32) {
    float w12[8];
    for (int c = 0; c < 8; ++c) {
      float s = 0.f;
      for (int b = 0; b < 16; ++b) s += hw1[a * 16 + b] * hw2[b * 8 + c];
      w12[c] = s;
    }
    float w123[4];
    for (int d = 0; d < 4; ++d) {
      float s = 0.f;
      for (int c = 0; c < 8; ++c) s += w12[c] * hw3[c * 4 + d];
      w123[d] = s;
    }
    float s = 0.f;
    for (int d = 0; d < 4; ++d) s += w123[d] * hw4[d];
    weff[a] = s;
  }
  if (a == 32) {
    float t2[8];
    for (int c = 0; c < 8; ++c) {
      float s = hb2[c];
      for (int b = 0; b < 16; ++b) s += hb1[b] * hw2[b * 8 + c];
      t2[c] = s;
    }
    float t3[4];
    for (int d = 0; d < 4; ++d) {
      float s = hb3[d];
      for (int c = 0; c < 8; ++c) s += t2[c] * hw3[c * 4 + d];
      t3[d] = s;
    }
    float s = hb4[0];
    for (int d = 0; d < 4; ++d) s += t3[d] * hw4[d];
    weff[32] = s;
  }
}

// ---- fused gates: [50000 x 160] @ [160 x 96] + LSTM gate math + ReLU ------
// block: 192 threads, 32 nodes. thread owns (j = tid%96, node-group tid/96).
__global__ __launch_bounds__(192) void k_gates(
    const float* __restrict__ T0, const float* __restrict__ T1,
    const float* __restrict__ T2, const float* __restrict__ T3,
    const float* __restrict__ T4, const float* __restrict__ Wt,
    const float* __restrict__ be, const float* __restrict__ wc2,
    float* __restrict__ Hout, int n) {
  __shared__ float Tlds[32 * 164];   // 32 nodes x 160 cols, padded
  __shared__ float preLds[32 * 97];  // 32 nodes x 96 gate pre-acts, padded
  int tid = threadIdx.x;
  int base = blockIdx.x * 32;

  for (int idx = tid; idx < 5 * 1024; idx += 192) {
    int tsel = idx >> 10;
    int rem = idx & 1023;
    int node = rem >> 5, fi = rem & 31;
    int gn = base + node;
    const float* Tp = (tsel == 0) ? T0 : (tsel == 1) ? T1 : (tsel == 2) ? T2
                      : (tsel == 3) ? T3 : T4;
    Tlds[node * 164 + tsel * 32 + fi] = (gn < n) ? Tp[gn * 32 + fi] : 0.f;
  }
  __syncthreads();

  int j = tid % 96;
  int ng = tid / 96;
  float acc[16];
#pragma unroll
  for (int i = 0; i < 16; ++i) acc[i] = 0.f;

  for (int k4 = 0; k4 < 40; ++k4) {
    int k = k4 * 4;
    float w0 = Wt[(k + 0) * 96 + j];
    float w1 = Wt[(k + 1) * 96 + j];
    float w2 = Wt[(k + 2) * 96 + j];
    float w3 = Wt[(k + 3) * 96 + j];
#pragma unroll
    for (int i = 0; i < 16; ++i) {
      const float4 t =
          *reinterpret_cast<const float4*>(&Tlds[(ng * 16 + i) * 164 + k]);
      float a = acc[i];
      a = fmaf(t.x, w0, a);
      a = fmaf(t.y, w1, a);
      a = fmaf(t.z, w2, a);
      a = fmaf(t.w, w3, a);
      acc[i] = a;
    }
  }

  float bej = be[j];
#pragma unroll
  for (int i = 0; i < 16; ++i) preLds[(ng * 16 + i) * 97 + j] = acc[i] + bej;
  __syncthreads();

  for (int idx = tid; idx < 1024; idx += 192) {
    int node = idx >> 5, h = idx & 31;
    int gn = base + node;
    if (gn >= n) continue;
    float pi = preLds[node * 97 + h];
    float pc = preLds[node * 97 + 32 + h];
    float po = preLds[node * 97 + 64 + h];
    float I = 1.f / (1.f + expf(-pi));
    float Cn = I * tanhf(pc);
    float O = 1.f / (1.f + expf(-(po + wc2[h] * Cn)));
    Hout[gn * 32 + h] = fmaxf(O * tanhf(Cn), 0.f);
  }
}

// ---- head: out[n] = H2[n,:] . w_eff + b_eff -------------------------------
__global__ __launch_bounds__(TPB) void k_head(
    const float* __restrict__ H, const float* __restrict__ weff,
    float* __restrict__ out, int n) {
  int i = blockIdx.x * TPB + threadIdx.x;
  if (i >= n) return;
  const float4* hp = reinterpret_cast<const float4*>(H + i * 32);
  float s = weff[32];
#pragma unroll
  for (int q = 0; q < 8; ++q) {
    float4 v = hp[q];
    s = fmaf(v.x, weff[q * 4 + 0], s);
    s = fmaf(v.y, weff[q * 4 + 1], s);
    s = fmaf(v.z, weff[q * 4 + 2], s);
    s = fmaf(v.w, weff[q * 4 + 3], s);
  }
  out[i] = s;
}

extern "C" void kernel_launch(void* const* d_in, const int* in_sizes, int n_in,
                              void* d_out, int out_size, void* d_ws,
                              size_t ws_size, hipStream_t stream) {
  const float* x = (const float*)d_in[0];
  const int* ei = (const int*)d_in[1];
  const float* ew = (const float*)d_in[2];
  const float* l1_Wx = (const float*)d_in[3];
  const float* l1_bx = (const float*)d_in[4];
  const float* l1_bh = (const float*)d_in[6];
  const float* l1_wc = (const float*)d_in[7];
  const float* l1_b = (const float*)d_in[8];
  const float* l2_Wx = (const float*)d_in[9];
  const float* l2_bx = (const float*)d_in[10];
  const float* l2_bh = (const float*)d_in[12];
  const float* l2_wc = (const float*)d_in[13];
  const float* l2_b = (const float*)d_in[14];
  const float* hw1 = (const float*)d_in[15];
  const float* hb1 = (const float*)d_in[16];
  const float* hw2 = (const float*)d_in[17];
  const float* hb2 = (const float*)d_in[18];
  const float* hw3 = (const float*)d_in[19];
  const float* hb3 = (const float*)d_in[20];
  const float* hw4 = (const float*)d_in[21];
  const float* hb4 = (const float*)d_in[22];

  const int N = in_sizes[0] / 32;
  const int E = in_sizes[1] / 2;
  const size_t EPAD = (size_t)E + 16 * (size_t)N;  // padded CSR capacity

  // workspace carve-out (256B aligned)
  char* w = (char*)d_ws;
  auto alloc = [&](size_t bytes) -> void* {
    void* p = (void*)w;
    w += (bytes + 255) & ~(size_t)255;
    return p;
  };
  int* degi = (int*)alloc((size_t)NX * N * 4);  // contiguous with cnti for
  int* cnti = (int*)alloc((size_t)NX * N * 4);  // a single memset
  int* off8 = (int*)alloc((size_t)NX * N * 4);
  float* dinv = (float*)alloc((size_t)N * 4);
  int* rp = (int*)alloc((size_t)(N + 1) * 4);
  int* excl = (int*)alloc((size_t)N * 4);
  int* bsum = (int*)alloc(256 * 4);
  uint2* epk = (uint2*)alloc(EPAD * 8);
  float* T1 = (float*)alloc((size_t)N * 32 * 4);
  float* T2 = (float*)alloc((size_t)N * 32 * 4);
  float* T3 = (float*)alloc((size_t)N * 32 * 4);
  float* T4 = (float*)alloc((size_t)N * 32 * 4);
  float* H1 = (float*)alloc((size_t)N * 32 * 4);
  float* H2 = (float*)alloc((size_t)N * 32 * 4);
  float* Wt1 = (float*)alloc(160 * 96 * 4);
  float* be1 = (float*)alloc(96 * 4);
  float* Wt2 = (float*)alloc(160 * 96 * 4);
  float* be2 = (float*)alloc(96 * 4);
  float* weff = (float*)alloc(40 * 4);
  // rank overlays T1 (dead after k_edge_pass2; T1 written by first k_prop)
  int* rank = (int*)T1;

  const int gE = (E + TPB - 1) / TPB;
  const int gN = (N + TPB - 1) / TPB;
  const int gP = (N + 3) / 4;
  const int gG = (N + 31) / 32;

  hipMemsetAsync(degi, 0, (size_t)2 * NX * N * 4, stream);  // degi + cnti
  hipMemsetAsync(epk, 0, EPAD * 8, stream);                 // zero pads

  // CSR build
  k_edge_pass1<<<gE, TPB, 0, stream>>>(ei, ew, degi, cnti, rank, N, E);
  k_scan1<<<gN, TPB, 0, stream>>>(cnti, excl, bsum, N);
  k_scan2<<<1, TPB, 0, stream>>>(bsum, gN);
  k_scan3<<<gN, TPB, 0, stream>>>(excl, bsum, degi, cnti, rp, off8, dinv, N);
  k_edge_pass2<<<gE, TPB, 0, stream>>>(ei, ew, dinv, off8, rank, epk, N, E);

  // weight prep
  k_build_wt<<<60, TPB, 0, stream>>>(l1_Wx, l1_bx, l1_bh, l1_b, Wt1, be1);
  k_build_wt<<<60, TPB, 0, stream>>>(l2_Wx, l2_bx, l2_bh, l2_b, Wt2, be2);
  k_head_setup<<<1, 64, 0, stream>>>(hw1, hb1, hw2, hb2, hw3, hb3, hw4, hb4,
                                     weff);

  // layer 1 (T0 = x)
  k_prop<<<gP, TPB, 0, stream>>>(x, rp, epk, nullptr, 1.f, 0.f, T1, N);
  k_prop<<<gP, TPB, 0, stream>>>(T1, rp, epk, x, 2.f, -1.f, T2, N);
  k_prop<<<gP, TPB, 0, stream>>>(T2, rp, epk, T1, 2.f, -1.f, T3, N);
  k_prop<<<gP, TPB, 0, stream>>>(T3, rp, epk, T2, 2.f, -1.f, T4, N);
  k_gates<<<gG, 192, 0, stream>>>(x, T1, T2, T3, T4, Wt1, be1, l1_wc + 64, H1,
                                  N);

  // layer 2 (T0 = H1)
  k_prop<<<gP, TPB, 0, stream>>>(H1, rp, epk, nullptr, 1.f, 0.f, T1, N);
  k_prop<<<gP, TPB, 0, stream>>>(T1, rp, epk, H1, 2.f, -1.f, T2, N);
  k_prop<<<gP, TPB, 0, stream>>>(T2, rp, epk, T1, 2.f, -1.f, T3, N);
  k_prop<<<gP, TPB, 0, stream>>>(T3, rp, epk, T2, 2.f, -1.f, T4, N);
  k_gates<<<gG, 192, 0, stream>>>(H1, T1, T2, T3, T4, Wt2, be2, l2_wc + 64, H2,
                                  N);

  // head
  k_head<<<gN, TPB, 0, stream>>>(H2, weff, (float*)d_out, N);
}

// Round 5
// 535.348 us; speedup vs baseline: 2.1686x; 1.1954x over previous
//
#include <hip/hip_runtime.h>
#include <math.h>

// ---------------------------------------------------------------------------
// RecurrentGCN: 2x GConvLSTM(Cheb K=5) + ReLU + collapsed 4-linear head.
// Simplifications (H=C=0 at t=0): cheb(H=0)==bh (bias only); forget gate dead;
// head linears compose to single affine w_eff[32], b_eff.
// R4 changes: CSR build rebuilt as a two-level LDS counting sort. R2/R3
// post-mortems showed global atomics execute memory-side on MI355X
// (~21 G/s, 32B write-through each; scope hints ignored) -> the 3.2M-atomic
// histogram (150us) + scatter (70us) are replaced by:
//   k_bucket: per-block LDS bucket histograms (391 buckets x 128 nodes),
//             1 global atomic per (block,bucket) (153K total), scatter
//             (src,ew) to per-bucket arenas (overlaid on dead T/H buffers).
//   k_deg:    per-bucket LDS float deg accumulation -> dinv. No atomics.
//   k_cnt:    per-bucket LDS histogram -> per-node counts.
//   k_csr:    per-bucket LDS cursors + fused norm -> final padded CSR.
// ---------------------------------------------------------------------------

#define TPB 256
#define PADM 15    // segment pad: round up to multiple of 16
#define BW 128     // nodes per bucket
#define NB 391     // ceil(50000/128)
#define CAP 6016   // per-bucket arena capacity (mean 4092, +30 sigma)
#define EPB 8192   // edges per k_bucket block

// ---- bucketing: one read pass, both src- and dst-bucketed arenas ----------
__global__ __launch_bounds__(512) void k_bucket(
    const int* __restrict__ ei, const float* __restrict__ ew,
    int* __restrict__ dcnt, int* __restrict__ scnt, uint2* __restrict__ arD,
    uint2* __restrict__ arS, int E) {
  __shared__ int hd[NB], hs[NB];  // per-block histograms
  __shared__ int cd[NB], cs[NB];  // global-base cursors
  int tid = threadIdx.x;
  int base = blockIdx.x * EPB;
  int end = min(base + EPB, E);
  for (int j = tid; j < NB; j += 512) {
    hd[j] = 0;
    hs[j] = 0;
  }
  __syncthreads();
  for (int i = base + tid; i < end; i += 512) {
    int s = ei[i], d = ei[E + i];
    atomicAdd(&hs[s >> 7], 1);
    atomicAdd(&hd[d >> 7], 1);
  }
  __syncthreads();
  for (int j = tid; j < NB; j += 512) {
    cd[j] = (hd[j] > 0) ? atomicAdd(&dcnt[j], hd[j]) : 0;
    cs[j] = (hs[j] > 0) ? atomicAdd(&scnt[j], hs[j]) : 0;
  }
  __syncthreads();
  for (int i = base + tid; i < end; i += 512) {
    int s = ei[i], d = ei[E + i];
    unsigned wbits = __float_as_uint(ew[i]);
    int bs = s >> 7, bd = d >> 7;
    int ps = atomicAdd(&cs[bs], 1);
    int pd = atomicAdd(&cd[bd], 1);
    if (ps < CAP) arS[(size_t)bs * CAP + ps] = make_uint2((unsigned)s, wbits);
    if (pd < CAP)
      arD[(size_t)bd * CAP + pd] =
          make_uint2((unsigned)s | ((unsigned)(d & 127) << 16), wbits);
  }
}

// ---- per-bucket degree accumulation -> dinv (LDS float adds only) ---------
__global__ __launch_bounds__(TPB) void k_deg(
    const uint2* __restrict__ arS, const int* __restrict__ scnt,
    float* __restrict__ dinv, int N) {
  __shared__ float dacc[BW];
  int b = blockIdx.x, tid = threadIdx.x;
  if (tid < BW) dacc[tid] = 0.f;
  __syncthreads();
  int nb = scnt[b];
  const uint2* p = arS + (size_t)b * CAP;
  for (int i = tid; i < nb; i += TPB) {
    uint2 e = p[i];
    atomicAdd(&dacc[e.x & 127], __uint_as_float(e.y));
  }
  __syncthreads();
  int node = b * BW + tid;
  if (tid < BW && node < N) {
    float dg = dacc[tid];
    dinv[node] = (dg > 0.f) ? 1.0f / sqrtf(fmaxf(dg, 1e-12f)) : 0.f;
  }
}

// ---- per-bucket in-degree counts -> cnt[node] -----------------------------
__global__ __launch_bounds__(TPB) void k_cnt(
    const uint2* __restrict__ arD, const int* __restrict__ dcnt,
    int* __restrict__ cnt, int N) {
  __shared__ int c[BW];
  int b = blockIdx.x, tid = threadIdx.x;
  if (tid < BW) c[tid] = 0;
  __syncthreads();
  int nb = dcnt[b];
  const uint2* p = arD + (size_t)b * CAP;
  for (int i = tid; i < nb; i += TPB) {
    atomicAdd(&c[(p[i].x >> 16) & 127], 1);
  }
  __syncthreads();
  int node = b * BW + tid;
  if (tid < BW && node < N) cnt[node] = c[tid];
}

// ---- 3-kernel exclusive scan of padded counts -----------------------------
__global__ __launch_bounds__(TPB) void k_scan1(
    const int* __restrict__ cnt, int* __restrict__ excl, int* __restrict__ bsum,
    int n) {
  __shared__ int sh[TPB];
  int tid = threadIdx.x;
  int i = blockIdx.x * TPB + tid;
  int v = (i < n) ? ((cnt[i] + PADM) & ~PADM) : 0;
  sh[tid] = v;
  __syncthreads();
  for (int off = 1; off < TPB; off <<= 1) {
    int t = (tid >= off) ? sh[tid - off] : 0;
    __syncthreads();
    sh[tid] += t;
    __syncthreads();
  }
  if (i < n) excl[i] = sh[tid] - v;
  if (tid == TPB - 1) bsum[blockIdx.x] = sh[TPB - 1];
}

__global__ __launch_bounds__(TPB) void k_scan2(int* __restrict__ bsum, int nb) {
  __shared__ int sh[TPB];
  int tid = threadIdx.x;
  int v = (tid < nb) ? bsum[tid] : 0;
  sh[tid] = v;
  __syncthreads();
  for (int off = 1; off < TPB; off <<= 1) {
    int t = (tid >= off) ? sh[tid - off] : 0;
    __syncthreads();
    sh[tid] += t;
    __syncthreads();
  }
  if (tid < nb) bsum[tid] = sh[tid] - v;
}

__global__ __launch_bounds__(TPB) void k_scan3(
    const int* __restrict__ excl, const int* __restrict__ bsum,
    const int* __restrict__ cnt, int* __restrict__ rp, int n) {
  int i = blockIdx.x * TPB + threadIdx.x;
  if (i < n) {
    int r = excl[i] + bsum[i >> 8];
    rp[i] = r;
    if (i == n - 1) rp[n] = r + ((cnt[i] + PADM) & ~PADM);
  }
}

// ---- final CSR scatter: LDS cursors + fused norm --------------------------
__global__ __launch_bounds__(TPB) void k_csr(
    const uint2* __restrict__ arD, const int* __restrict__ dcnt,
    const int* __restrict__ rp, const float* __restrict__ dinv,
    uint2* __restrict__ epk, int N) {
  __shared__ int cur[BW];
  __shared__ float dloc[BW];
  int b = blockIdx.x, tid = threadIdx.x;
  int node = b * BW + tid;
  if (tid < BW) {
    cur[tid] = (node < N) ? rp[node] : 0;
    dloc[tid] = (node < N) ? dinv[node] : 0.f;
  }
  __syncthreads();
  int nb = dcnt[b];
  const uint2* p = arD + (size_t)b * CAP;
  for (int i = tid; i < nb; i += TPB) {
    uint2 e = p[i];
    int src = e.x & 0xFFFF;
    int dl = (e.x >> 16) & 127;
    float nv = -dinv[src] * __uint_as_float(e.y) * dloc[dl];
    int pos = atomicAdd(&cur[dl], 1);
    epk[pos] = make_uint2((unsigned)src, __float_as_uint(nv));
  }
}

// ---- sparse prop: y[dst] = alpha * sum_e norm_e * x[src_e] + beta * prev --
// One node per wave64: 8 edge-slots x 8 feature-quad lanes (float4).
// Padded CSR (x16, zero pads) -> branch-free unroll-2: 16 edges in flight.
__global__ __launch_bounds__(TPB) void k_prop(
    const float* __restrict__ xin, const int* __restrict__ rp,
    const uint2* __restrict__ epk, const float* __restrict__ prev,
    float alpha, float beta, float* __restrict__ yout, int n) {
  int tid = threadIdx.x;
  int node = blockIdx.x * 4 + (tid >> 6);
  if (node >= n) return;
  int lane = tid & 63;
  int slot = lane >> 3;  // 0..7 edge slot
  int fq = lane & 7;     // feature quad: features [4fq, 4fq+4)
  int b = rp[node], e = rp[node + 1];
  float4 a0 = make_float4(0.f, 0.f, 0.f, 0.f);
  float4 a1 = a0;
  for (int t = b + slot; t < e; t += 16) {
    uint2 p0 = epk[t];
    uint2 p1 = epk[t + 8];
    const float4 x0 =
        *reinterpret_cast<const float4*>(&xin[(size_t)p0.x * 32 + (fq << 2)]);
    const float4 x1 =
        *reinterpret_cast<const float4*>(&xin[(size_t)p1.x * 32 + (fq << 2)]);
    float n0 = __uint_as_float(p0.y);
    float n1 = __uint_as_float(p1.y);
    a0.x = fmaf(n0, x0.x, a0.x);
    a0.y = fmaf(n0, x0.y, a0.y);
    a0.z = fmaf(n0, x0.z, a0.z);
    a0.w = fmaf(n0, x0.w, a0.w);
    a1.x = fmaf(n1, x1.x, a1.x);
    a1.y = fmaf(n1, x1.y, a1.y);
    a1.z = fmaf(n1, x1.z, a1.z);
    a1.w = fmaf(n1, x1.w, a1.w);
  }
  float4 acc;
  acc.x = a0.x + a1.x;
  acc.y = a0.y + a1.y;
  acc.z = a0.z + a1.z;
  acc.w = a0.w + a1.w;
#pragma unroll
  for (int m = 8; m <= 32; m <<= 1) {
    acc.x += __shfl_xor(acc.x, m);
    acc.y += __shfl_xor(acc.y, m);
    acc.z += __shfl_xor(acc.z, m);
    acc.w += __shfl_xor(acc.w, m);
  }
  if (slot == 0) {
    float4 r;
    r.x = alpha * acc.x;
    r.y = alpha * acc.y;
    r.z = alpha * acc.z;
    r.w = alpha * acc.w;
    if (prev != nullptr) {
      const float4 pv = *reinterpret_cast<const float4*>(
          &prev[(size_t)node * 32 + (fq << 2)]);
      r.x = fmaf(beta, pv.x, r.x);
      r.y = fmaf(beta, pv.y, r.y);
      r.z = fmaf(beta, pv.z, r.z);
      r.w = fmaf(beta, pv.w, r.w);
    }
    *reinterpret_cast<float4*>(&yout[(size_t)node * 32 + (fq << 2)]) = r;
  }
}

// ---- weight prep: Wt[k][j] (k=kk*32+i in 0..159, j=g3*32+h in 0..95) ------
// gates kept: g3=0 -> i (gate 0), g3=1 -> c (gate 2), g3=2 -> o (gate 3)
__global__ __launch_bounds__(TPB) void k_build_wt(
    const float* __restrict__ Wx, const float* __restrict__ bx,
    const float* __restrict__ bh, const float* __restrict__ bb,
    float* __restrict__ Wt, float* __restrict__ be) {
  int idx = blockIdx.x * TPB + threadIdx.x;
  if (idx < 160 * 96) {
    int k = idx / 96, j = idx % 96;
    int kk = k >> 5, i = k & 31;
    int g3 = j >> 5, h = j & 31;
    int g = (g3 == 0) ? 0 : (g3 == 1 ? 2 : 3);
    Wt[idx] = Wx[((g * 5 + kk) * 32 + i) * 32 + h];
  }
  if (idx < 96) {
    int g3 = idx >> 5, h = idx & 31;
    int g = (g3 == 0) ? 0 : (g3 == 1 ? 2 : 3);
    be[idx] = bx[g * 32 + h] + bh[g * 32 + h] + bb[g * 32 + h];
  }
}

// ---- head collapse: w_eff = hw1@hw2@hw3@hw4, b_eff similarly --------------
__global__ void k_head_setup(
    const float* __restrict__ hw1, const float* __restrict__ hb1,
    const float* __restrict__ hw2, const float* __restrict__ hb2,
    const float* __restrict__ hw3, const float* __restrict__ hb3,
    const float* __restrict__ hw4, const float* __restrict__ hb4,
    float* __restrict__ weff) {
  int a = threadIdx.x;
  if (a < 32) {
    float w12[8];
    for (int c = 0; c < 8; ++c) {
      float s = 0.f;
      for (int b = 0; b < 16; ++b) s += hw1[a * 16 + b] * hw2[b * 8 + c];
      w12[c] = s;
    }
    float w123[4];
    for (int d = 0; d < 4; ++d) {
      float s = 0.f;
      for (int c = 0; c < 8; ++c) s += w12[c] * hw3[c * 4 + d];
      w123[d] = s;
    }
    float s = 0.f;
    for (int d = 0; d < 4; ++d) s += w123[d] * hw4[d];
    weff[a] = s;
  }
  if (a == 32) {
    float t2[8];
    for (int c = 0; c < 8; ++c) {
      float s = hb2[c];
      for (int b = 0; b < 16; ++b) s += hb1[b] * hw2[b * 8 + c];
      t2[c] = s;
    }
    float t3[4];
    for (int d = 0; d < 4; ++d) {
      float s = hb3[d];
      for (int c = 0; c < 8; ++c) s += t2[c] * hw3[c * 4 + d];
      t3[d] = s;
    }
    float s = hb4[0];
    for (int d = 0; d < 4; ++d) s += t3[d] * hw4[d];
    weff[32] = s;
  }
}

// ---- fused gates: [50000 x 160] @ [160 x 96] + LSTM gate math + ReLU ------
// block: 192 threads, 32 nodes. thread owns (j = tid%96, node-group tid/96).
__global__ __launch_bounds__(192) void k_gates(
    const float* __restrict__ T0, const float* __restrict__ T1,
    const float* __restrict__ T2, const float* __restrict__ T3,
    const float* __restrict__ T4, const float* __restrict__ Wt,
    const float* __restrict__ be, const float* __restrict__ wc2,
    float* __restrict__ Hout, int n) {
  __shared__ float Tlds[32 * 164];   // 32 nodes x 160 cols, padded
  __shared__ float preLds[32 * 97];  // 32 nodes x 96 gate pre-acts, padded
  int tid = threadIdx.x;
  int base = blockIdx.x * 32;

  for (int idx = tid; idx < 5 * 1024; idx += 192) {
    int tsel = idx >> 10;
    int rem = idx & 1023;
    int node = rem >> 5, fi = rem & 31;
    int gn = base + node;
    const float* Tp = (tsel == 0) ? T0 : (tsel == 1) ? T1 : (tsel == 2) ? T2
                      : (tsel == 3) ? T3 : T4;
    Tlds[node * 164 + tsel * 32 + fi] = (gn < n) ? Tp[gn * 32 + fi] : 0.f;
  }
  __syncthreads();

  int j = tid % 96;
  int ng = tid / 96;
  float acc[16];
#pragma unroll
  for (int i = 0; i < 16; ++i) acc[i] = 0.f;

  for (int k4 = 0; k4 < 40; ++k4) {
    int k = k4 * 4;
    float w0 = Wt[(k + 0) * 96 + j];
    float w1 = Wt[(k + 1) * 96 + j];
    float w2 = Wt[(k + 2) * 96 + j];
    float w3 = Wt[(k + 3) * 96 + j];
#pragma unroll
    for (int i = 0; i < 16; ++i) {
      const float4 t =
          *reinterpret_cast<const float4*>(&Tlds[(ng * 16 + i) * 164 + k]);
      float a = acc[i];
      a = fmaf(t.x, w0, a);
      a = fmaf(t.y, w1, a);
      a = fmaf(t.z, w2, a);
      a = fmaf(t.w, w3, a);
      acc[i] = a;
    }
  }

  float bej = be[j];
#pragma unroll
  for (int i = 0; i < 16; ++i) preLds[(ng * 16 + i) * 97 + j] = acc[i] + bej;
  __syncthreads();

  for (int idx = tid; idx < 1024; idx += 192) {
    int node = idx >> 5, h = idx & 31;
    int gn = base + node;
    if (gn >= n) continue;
    float pi = preLds[node * 97 + h];
    float pc = preLds[node * 97 + 32 + h];
    float po = preLds[node * 97 + 64 + h];
    float I = 1.f / (1.f + expf(-pi));
    float Cn = I * tanhf(pc);
    float O = 1.f / (1.f + expf(-(po + wc2[h] * Cn)));
    Hout[gn * 32 + h] = fmaxf(O * tanhf(Cn), 0.f);
  }
}

// ---- head: out[n] = H2[n,:] . w_eff + b_eff -------------------------------
__global__ __launch_bounds__(TPB) void k_head(
    const float* __restrict__ H, const float* __restrict__ weff,
    float* __restrict__ out, int n) {
  int i = blockIdx.x * TPB + threadIdx.x;
  if (i >= n) return;
  const float4* hp = reinterpret_cast<const float4*>(H + i * 32);
  float s = weff[32];
#pragma unroll
  for (int q = 0; q < 8; ++q) {
    float4 v = hp[q];
    s = fmaf(v.x, weff[q * 4 + 0], s);
    s = fmaf(v.y, weff[q * 4 + 1], s);
    s = fmaf(v.z, weff[q * 4 + 2], s);
    s = fmaf(v.w, weff[q * 4 + 3], s);
  }
  out[i] = s;
}

extern "C" void kernel_launch(void* const* d_in, const int* in_sizes, int n_in,
                              void* d_out, int out_size, void* d_ws,
                              size_t ws_size, hipStream_t stream) {
  const float* x = (const float*)d_in[0];
  const int* ei = (const int*)d_in[1];
  const float* ew = (const float*)d_in[2];
  const float* l1_Wx = (const float*)d_in[3];
  const float* l1_bx = (const float*)d_in[4];
  const float* l1_bh = (const float*)d_in[6];
  const float* l1_wc = (const float*)d_in[7];
  const float* l1_b = (const float*)d_in[8];
  const float* l2_Wx = (const float*)d_in[9];
  const float* l2_bx = (const float*)d_in[10];
  const float* l2_bh = (const float*)d_in[12];
  const float* l2_wc = (const float*)d_in[13];
  const float* l2_b = (const float*)d_in[14];
  const float* hw1 = (const float*)d_in[15];
  const float* hb1 = (const float*)d_in[16];
  const float* hw2 = (const float*)d_in[17];
  const float* hb2 = (const float*)d_in[18];
  const float* hw3 = (const float*)d_in[19];
  const float* hb3 = (const float*)d_in[20];
  const float* hw4 = (const float*)d_in[21];
  const float* hb4 = (const float*)d_in[22];

  const int N = in_sizes[0] / 32;
  const int E = in_sizes[1] / 2;
  const size_t EPAD = (size_t)E + 16 * (size_t)N;  // padded CSR capacity

  // workspace carve-out (256B aligned)
  char* w = (char*)d_ws;
  auto alloc = [&](size_t bytes) -> void* {
    void* p = (void*)w;
    w += (bytes + 255) & ~(size_t)255;
    return p;
  };
  float* dinv = (float*)alloc((size_t)N * 4);
  int* cnt = (int*)alloc((size_t)N * 4);
  int* rp = (int*)alloc((size_t)(N + 1) * 4);
  int* excl = (int*)alloc((size_t)N * 4);
  int* bsum = (int*)alloc(256 * 4);
  int* dcnt = (int*)alloc(512 * 4);  // contiguous with scnt: single memset
  int* scnt = (int*)alloc(512 * 4);
  uint2* epk = (uint2*)alloc(EPAD * 8);
  float* T1 = (float*)alloc((size_t)N * 32 * 4);
  float* T2 = (float*)alloc((size_t)N * 32 * 4);
  float* T3 = (float*)alloc((size_t)N * 32 * 4);
  float* T4 = (float*)alloc((size_t)N * 32 * 4);
  float* H1 = (float*)alloc((size_t)N * 32 * 4);
  float* H2 = (float*)alloc((size_t)N * 32 * 4);
  float* Wt1 = (float*)alloc(160 * 96 * 4);
  float* be1 = (float*)alloc(96 * 4);
  float* Wt2 = (float*)alloc(160 * 96 * 4);
  float* be2 = (float*)alloc(96 * 4);
  float* weff = (float*)alloc(40 * 4);
  // arenas overlay T/H buffers (dead until props): NB*CAP*8 = 18.82MB each;
  // T1..T3 and T4..H2 are each 19.2MB contiguous.
  uint2* arS = (uint2*)T1;
  uint2* arD = (uint2*)T4;

  const int gBK = (E + EPB - 1) / EPB;
  const int gN = (N + TPB - 1) / TPB;
  const int gP = (N + 3) / 4;
  const int gG = (N + 31) / 32;

  hipMemsetAsync(dcnt, 0, 1024 * 4, stream);  // dcnt + scnt
  hipMemsetAsync(epk, 0, EPAD * 8, stream);   // zero pads

  // CSR build (two-level LDS counting sort)
  k_bucket<<<gBK, 512, 0, stream>>>(ei, ew, dcnt, scnt, arD, arS, E);
  k_deg<<<NB, TPB, 0, stream>>>(arS, scnt, dinv, N);
  k_cnt<<<NB, TPB, 0, stream>>>(arD, dcnt, cnt, N);
  k_scan1<<<gN, TPB, 0, stream>>>(cnt, excl, bsum, N);
  k_scan2<<<1, TPB, 0, stream>>>(bsum, gN);
  k_scan3<<<gN, TPB, 0, stream>>>(excl, bsum, cnt, rp, N);
  k_csr<<<NB, TPB, 0, stream>>>(arD, dcnt, rp, dinv, epk, N);

  // weight prep
  k_build_wt<<<60, TPB, 0, stream>>>(l1_Wx, l1_bx, l1_bh, l1_b, Wt1, be1);
  k_build_wt<<<60, TPB, 0, stream>>>(l2_Wx, l2_bx, l2_bh, l2_b, Wt2, be2);
  k_head_setup<<<1, 64, 0, stream>>>(hw1, hb1, hw2, hb2, hw3, hb3, hw4, hb4,
                                     weff);

  // layer 1 (T0 = x)
  k_prop<<<gP, TPB, 0, stream>>>(x, rp, epk, nullptr, 1.f, 0.f, T1, N);
  k_prop<<<gP, TPB, 0, stream>>>(T1, rp, epk, x, 2.f, -1.f, T2, N);
  k_prop<<<gP, TPB, 0, stream>>>(T2, rp, epk, T1, 2.f, -1.f, T3, N);
  k_prop<<<gP, TPB, 0, stream>>>(T3, rp, epk, T2, 2.f, -1.f, T4, N);
  k_gates<<<gG, 192, 0, stream>>>(x, T1, T2, T3, T4, Wt1, be1, l1_wc + 64, H1,
                                  N);

  // layer 2 (T0 = H1)
  k_prop<<<gP, TPB, 0, stream>>>(H1, rp, epk, nullptr, 1.f, 0.f, T1, N);
  k_prop<<<gP, TPB, 0, stream>>>(T1, rp, epk, H1, 2.f, -1.f, T2, N);
  k_prop<<<gP, TPB, 0, stream>>>(T2, rp, epk, T1, 2.f, -1.f, T3, N);
  k_prop<<<gP, TPB, 0, stream>>>(T3, rp, epk, T2, 2.f, -1.f, T4, N);
  k_gates<<<gG, 192, 0, stream>>>(H1, T1, T2, T3, T4, Wt2, be2, l2_wc + 64, H2,
                                  N);

  // head
  k_head<<<gN, TPB, 0, stream>>>(H2, weff, (float*)d_out, N);
}

// Round 6
// 509.592 us; speedup vs baseline: 2.2782x; 1.0505x over previous
//
#include <hip/hip_runtime.h>
#include <math.h>

// ---------------------------------------------------------------------------
// RecurrentGCN: 2x GConvLSTM(Cheb K=5) + ReLU + collapsed 4-linear head.
// Simplifications (H=C=0 at t=0): cheb(H=0)==bh (bias only); forget gate dead;
// head linears compose to single affine w_eff[32], b_eff.
// R5 changes: k_gates rebuilt (was LDS-read-bound at 4 B/FMA = ~59us floor):
//   lane = node, 64 nodes/block, wave w owns h-slice [8w,8w+8) of all 3
//   gates; per k4 one ds_read_b128 per lane feeds 96 FMAs (0.17 B/FMA);
//   weights pre-swizzled per-wave -> wave-uniform s_load_dwordx4; gate math
//   in-register, H staged through small padded LDS tile for coalesced store.
// k_prop: unroll 4 (32 edges in flight per wave).
// ---------------------------------------------------------------------------

#define TPB 256
#define PADM 15    // segment pad: round up to multiple of 16
#define BW 128     // nodes per bucket
#define NB 391     // ceil(50000/128)
#define CAP 6016   // per-bucket arena capacity (mean 4092, +30 sigma)
#define EPB 8192   // edges per k_bucket block

// ---- bucketing: one read pass, both src- and dst-bucketed arenas ----------
__global__ __launch_bounds__(512) void k_bucket(
    const int* __restrict__ ei, const float* __restrict__ ew,
    int* __restrict__ dcnt, int* __restrict__ scnt, uint2* __restrict__ arD,
    uint2* __restrict__ arS, int E) {
  __shared__ int hd[NB], hs[NB];  // per-block histograms
  __shared__ int cd[NB], cs[NB];  // global-base cursors
  int tid = threadIdx.x;
  int base = blockIdx.x * EPB;
  int end = min(base + EPB, E);
  for (int j = tid; j < NB; j += 512) {
    hd[j] = 0;
    hs[j] = 0;
  }
  __syncthreads();
  for (int i = base + tid; i < end; i += 512) {
    int s = ei[i], d = ei[E + i];
    atomicAdd(&hs[s >> 7], 1);
    atomicAdd(&hd[d >> 7], 1);
  }
  __syncthreads();
  for (int j = tid; j < NB; j += 512) {
    cd[j] = (hd[j] > 0) ? atomicAdd(&dcnt[j], hd[j]) : 0;
    cs[j] = (hs[j] > 0) ? atomicAdd(&scnt[j], hs[j]) : 0;
  }
  __syncthreads();
  for (int i = base + tid; i < end; i += 512) {
    int s = ei[i], d = ei[E + i];
    unsigned wbits = __float_as_uint(ew[i]);
    int bs = s >> 7, bd = d >> 7;
    int ps = atomicAdd(&cs[bs], 1);
    int pd = atomicAdd(&cd[bd], 1);
    if (ps < CAP) arS[(size_t)bs * CAP + ps] = make_uint2((unsigned)s, wbits);
    if (pd < CAP)
      arD[(size_t)bd * CAP + pd] =
          make_uint2((unsigned)s | ((unsigned)(d & 127) << 16), wbits);
  }
}

// ---- per-bucket degree accumulation -> dinv (LDS float adds only) ---------
__global__ __launch_bounds__(TPB) void k_deg(
    const uint2* __restrict__ arS, const int* __restrict__ scnt,
    float* __restrict__ dinv, int N) {
  __shared__ float dacc[BW];
  int b = blockIdx.x, tid = threadIdx.x;
  if (tid < BW) dacc[tid] = 0.f;
  __syncthreads();
  int nb = scnt[b];
  const uint2* p = arS + (size_t)b * CAP;
  for (int i = tid; i < nb; i += TPB) {
    uint2 e = p[i];
    atomicAdd(&dacc[e.x & 127], __uint_as_float(e.y));
  }
  __syncthreads();
  int node = b * BW + tid;
  if (tid < BW && node < N) {
    float dg = dacc[tid];
    dinv[node] = (dg > 0.f) ? 1.0f / sqrtf(fmaxf(dg, 1e-12f)) : 0.f;
  }
}

// ---- per-bucket in-degree counts -> cnt[node] -----------------------------
__global__ __launch_bounds__(TPB) void k_cnt(
    const uint2* __restrict__ arD, const int* __restrict__ dcnt,
    int* __restrict__ cnt, int N) {
  __shared__ int c[BW];
  int b = blockIdx.x, tid = threadIdx.x;
  if (tid < BW) c[tid] = 0;
  __syncthreads();
  int nb = dcnt[b];
  const uint2* p = arD + (size_t)b * CAP;
  for (int i = tid; i < nb; i += TPB) {
    atomicAdd(&c[(p[i].x >> 16) & 127], 1);
  }
  __syncthreads();
  int node = b * BW + tid;
  if (tid < BW && node < N) cnt[node] = c[tid];
}

// ---- 3-kernel exclusive scan of padded counts -----------------------------
__global__ __launch_bounds__(TPB) void k_scan1(
    const int* __restrict__ cnt, int* __restrict__ excl, int* __restrict__ bsum,
    int n) {
  __shared__ int sh[TPB];
  int tid = threadIdx.x;
  int i = blockIdx.x * TPB + tid;
  int v = (i < n) ? ((cnt[i] + PADM) & ~PADM) : 0;
  sh[tid] = v;
  __syncthreads();
  for (int off = 1; off < TPB; off <<= 1) {
    int t = (tid >= off) ? sh[tid - off] : 0;
    __syncthreads();
    sh[tid] += t;
    __syncthreads();
  }
  if (i < n) excl[i] = sh[tid] - v;
  if (tid == TPB - 1) bsum[blockIdx.x] = sh[TPB - 1];
}

__global__ __launch_bounds__(TPB) void k_scan2(int* __restrict__ bsum, int nb) {
  __shared__ int sh[TPB];
  int tid = threadIdx.x;
  int v = (tid < nb) ? bsum[tid] : 0;
  sh[tid] = v;
  __syncthreads();
  for (int off = 1; off < TPB; off <<= 1) {
    int t = (tid >= off) ? sh[tid - off] : 0;
    __syncthreads();
    sh[tid] += t;
    __syncthreads();
  }
  if (tid < nb) bsum[tid] = sh[tid] - v;
}

__global__ __launch_bounds__(TPB) void k_scan3(
    const int* __restrict__ excl, const int* __restrict__ bsum,
    const int* __restrict__ cnt, int* __restrict__ rp, int n) {
  int i = blockIdx.x * TPB + threadIdx.x;
  if (i < n) {
    int r = excl[i] + bsum[i >> 8];
    rp[i] = r;
    if (i == n - 1) rp[n] = r + ((cnt[i] + PADM) & ~PADM);
  }
}

// ---- final CSR scatter: LDS cursors + fused norm --------------------------
__global__ __launch_bounds__(TPB) void k_csr(
    const uint2* __restrict__ arD, const int* __restrict__ dcnt,
    const int* __restrict__ rp, const float* __restrict__ dinv,
    uint2* __restrict__ epk, int N) {
  __shared__ int cur[BW];
  __shared__ float dloc[BW];
  int b = blockIdx.x, tid = threadIdx.x;
  int node = b * BW + tid;
  if (tid < BW) {
    cur[tid] = (node < N) ? rp[node] : 0;
    dloc[tid] = (node < N) ? dinv[node] : 0.f;
  }
  __syncthreads();
  int nb = dcnt[b];
  const uint2* p = arD + (size_t)b * CAP;
  for (int i = tid; i < nb; i += TPB) {
    uint2 e = p[i];
    int src = e.x & 0xFFFF;
    int dl = (e.x >> 16) & 127;
    float nv = -dinv[src] * __uint_as_float(e.y) * dloc[dl];
    int pos = atomicAdd(&cur[dl], 1);
    epk[pos] = make_uint2((unsigned)src, __float_as_uint(nv));
  }
}

// ---- sparse prop: y[dst] = alpha * sum_e norm_e * x[src_e] + beta * prev --
// One node per wave64: 8 edge-slots x 8 feature-quad lanes (float4).
// Padded CSR (x16, zero pads); unroll 4 -> 32 edges in flight per wave.
__global__ __launch_bounds__(TPB) void k_prop(
    const float* __restrict__ xin, const int* __restrict__ rp,
    const uint2* __restrict__ epk, const float* __restrict__ prev,
    float alpha, float beta, float* __restrict__ yout, int n) {
  int tid = threadIdx.x;
  int node = blockIdx.x * 4 + (tid >> 6);
  if (node >= n) return;
  int lane = tid & 63;
  int slot = lane >> 3;  // 0..7 edge slot
  int fq = lane & 7;     // feature quad: features [4fq, 4fq+4)
  const float* xf = xin + (fq << 2);
  int b = rp[node], e = rp[node + 1];
  float4 a0 = make_float4(0.f, 0.f, 0.f, 0.f);
  float4 a1 = a0, a2 = a0, a3 = a0;
  int t = b + slot;
  for (; t + 24 < e; t += 32) {
    uint2 p0 = epk[t];
    uint2 p1 = epk[t + 8];
    uint2 p2 = epk[t + 16];
    uint2 p3 = epk[t + 24];
    const float4 x0 = *reinterpret_cast<const float4*>(&xf[(size_t)p0.x * 32]);
    const float4 x1 = *reinterpret_cast<const float4*>(&xf[(size_t)p1.x * 32]);
    const float4 x2 = *reinterpret_cast<const float4*>(&xf[(size_t)p2.x * 32]);
    const float4 x3 = *reinterpret_cast<const float4*>(&xf[(size_t)p3.x * 32]);
    float n0 = __uint_as_float(p0.y), n1 = __uint_as_float(p1.y);
    float n2 = __uint_as_float(p2.y), n3 = __uint_as_float(p3.y);
    a0.x = fmaf(n0, x0.x, a0.x);
    a0.y = fmaf(n0, x0.y, a0.y);
    a0.z = fmaf(n0, x0.z, a0.z);
    a0.w = fmaf(n0, x0.w, a0.w);
    a1.x = fmaf(n1, x1.x, a1.x);
    a1.y = fmaf(n1, x1.y, a1.y);
    a1.z = fmaf(n1, x1.z, a1.z);
    a1.w = fmaf(n1, x1.w, a1.w);
    a2.x = fmaf(n2, x2.x, a2.x);
    a2.y = fmaf(n2, x2.y, a2.y);
    a2.z = fmaf(n2, x2.z, a2.z);
    a2.w = fmaf(n2, x2.w, a2.w);
    a3.x = fmaf(n3, x3.x, a3.x);
    a3.y = fmaf(n3, x3.y, a3.y);
    a3.z = fmaf(n3, x3.z, a3.z);
    a3.w = fmaf(n3, x3.w, a3.w);
  }
  if (t < e) {  // one remaining 16-edge step (segments are padded to x16)
    uint2 p0 = epk[t];
    uint2 p1 = epk[t + 8];
    const float4 x0 = *reinterpret_cast<const float4*>(&xf[(size_t)p0.x * 32]);
    const float4 x1 = *reinterpret_cast<const float4*>(&xf[(size_t)p1.x * 32]);
    float n0 = __uint_as_float(p0.y), n1 = __uint_as_float(p1.y);
    a0.x = fmaf(n0, x0.x, a0.x);
    a0.y = fmaf(n0, x0.y, a0.y);
    a0.z = fmaf(n0, x0.z, a0.z);
    a0.w = fmaf(n0, x0.w, a0.w);
    a1.x = fmaf(n1, x1.x, a1.x);
    a1.y = fmaf(n1, x1.y, a1.y);
    a1.z = fmaf(n1, x1.z, a1.z);
    a1.w = fmaf(n1, x1.w, a1.w);
  }
  float4 acc;
  acc.x = (a0.x + a2.x) + (a1.x + a3.x);
  acc.y = (a0.y + a2.y) + (a1.y + a3.y);
  acc.z = (a0.z + a2.z) + (a1.z + a3.z);
  acc.w = (a0.w + a2.w) + (a1.w + a3.w);
#pragma unroll
  for (int m = 8; m <= 32; m <<= 1) {
    acc.x += __shfl_xor(acc.x, m);
    acc.y += __shfl_xor(acc.y, m);
    acc.z += __shfl_xor(acc.z, m);
    acc.w += __shfl_xor(acc.w, m);
  }
  if (slot == 0) {
    float4 r;
    r.x = alpha * acc.x;
    r.y = alpha * acc.y;
    r.z = alpha * acc.z;
    r.w = alpha * acc.w;
    if (prev != nullptr) {
      const float4 pv = *reinterpret_cast<const float4*>(
          &prev[(size_t)node * 32 + (fq << 2)]);
      r.x = fmaf(beta, pv.x, r.x);
      r.y = fmaf(beta, pv.y, r.y);
      r.z = fmaf(beta, pv.z, r.z);
      r.w = fmaf(beta, pv.w, r.w);
    }
    *reinterpret_cast<float4*>(&yout[(size_t)node * 32 + (fq << 2)]) = r;
  }
}

// ---- weight prep: wts[w][g3][hh][k] (wave-sliced), be[g3*32+h] ------------
// gates kept: g3=0 -> i (gate 0), g3=1 -> c (gate 2), g3=2 -> o (gate 3)
__global__ __launch_bounds__(TPB) void k_build_wt(
    const float* __restrict__ Wx, const float* __restrict__ bx,
    const float* __restrict__ bh, const float* __restrict__ bb,
    float* __restrict__ wts, float* __restrict__ be) {
  int idx = blockIdx.x * TPB + threadIdx.x;
  if (idx < 96 * 160) {
    int jj = idx / 160, k = idx % 160;
    int w = jj / 24, r = jj % 24;
    int g3 = r >> 3, hh = r & 7;
    int h = w * 8 + hh;
    int kk = k >> 5, i = k & 31;
    int g = (g3 == 0) ? 0 : (g3 == 1 ? 2 : 3);
    wts[idx] = Wx[((g * 5 + kk) * 32 + i) * 32 + h];
  }
  if (idx < 96) {
    int g3 = idx >> 5, h = idx & 31;
    int g = (g3 == 0) ? 0 : (g3 == 1 ? 2 : 3);
    be[idx] = bx[g * 32 + h] + bh[g * 32 + h] + bb[g * 32 + h];
  }
}

// ---- head collapse: w_eff = hw1@hw2@hw3@hw4, b_eff similarly --------------
__global__ void k_head_setup(
    const float* __restrict__ hw1, const float* __restrict__ hb1,
    const float* __restrict__ hw2, const float* __restrict__ hb2,
    const float* __restrict__ hw3, const float* __restrict__ hb3,
    const float* __restrict__ hw4, const float* __restrict__ hb4,
    float* __restrict__ weff) {
  int a = threadIdx.x;
  if (a < 32) {
    float w12[8];
    for (int c = 0; c < 8; ++c) {
      float s = 0.f;
      for (int b = 0; b < 16; ++b) s += hw1[a * 16 + b] * hw2[b * 8 + c];
      w12[c] = s;
    }
    float w123[4];
    for (int d = 0; d < 4; ++d) {
      float s = 0.f;
      for (int c = 0; c < 8; ++c) s += w12[c] * hw3[c * 4 + d];
      w123[d] = s;
    }
    float s = 0.f;
    for (int d = 0; d < 4; ++d) s += w123[d] * hw4[d];
    weff[a] = s;
  }
  if (a == 32) {
    float t2[8];
    for (int c = 0; c < 8; ++c) {
      float s = hb2[c];
      for (int b = 0; b < 16; ++b) s += hb1[b] * hw2[b * 8 + c];
      t2[c] = s;
    }
    float t3[4];
    for (int d = 0; d < 4; ++d) {
      float s = hb3[d];
      for (int c = 0; c < 8; ++c) s += t2[c] * hw3[c * 4 + d];
      t3[d] = s;
    }
    float s = hb4[0];
    for (int d = 0; d < 4; ++d) s += t3[d] * hw4[d];
    weff[32] = s;
  }
}

// ---- fused gates: [50000 x 160] @ [160 x 96] + LSTM gate math + ReLU ------
// block: 256 threads = 4 waves, 64 nodes; lane = node. Wave w owns h-slice
// [8w, 8w+8) of all 3 gates (acc[3][8]); weights via wave-uniform s_load;
// one ds_read_b128 per lane per k4 feeds 96 FMAs.
__global__ __launch_bounds__(256) void k_gates(
    const float* __restrict__ T0, const float* __restrict__ T1,
    const float* __restrict__ T2, const float* __restrict__ T3,
    const float* __restrict__ T4, const float* __restrict__ wts,
    const float* __restrict__ be, const float* __restrict__ wc2,
    float* __restrict__ Hout, int n) {
  __shared__ float Tl[64][164];  // stride 164: 16B-aligned rows, phase-4 banks
  __shared__ float Hl[64][33];
  int tid = threadIdx.x;
  int base = blockIdx.x * 64;

  for (int q = tid; q < 2560; q += 256) {  // 5 mats x 64 nodes x 8 quads
    int tsel = q >> 9;
    int rem = q & 511;
    int node = rem >> 3, fq = rem & 7;
    int gn = base + node;
    const float* Tp = (tsel == 0) ? T0 : (tsel == 1) ? T1 : (tsel == 2) ? T2
                      : (tsel == 3) ? T3 : T4;
    float4 v = make_float4(0.f, 0.f, 0.f, 0.f);
    if (gn < n) v = *reinterpret_cast<const float4*>(&Tp[gn * 32 + fq * 4]);
    *reinterpret_cast<float4*>(&Tl[node][tsel * 32 + fq * 4]) = v;
  }
  __syncthreads();

  int w = __builtin_amdgcn_readfirstlane(tid >> 6);
  int lane = tid & 63;
  float acc[3][8];
#pragma unroll
  for (int g = 0; g < 3; ++g)
#pragma unroll
    for (int hh = 0; hh < 8; ++hh) acc[g][hh] = 0.f;

  const float* wp = wts + w * 3840;  // wave's [3][8][160] slice
  for (int k4 = 0; k4 < 40; ++k4) {
    const float4 t = *reinterpret_cast<const float4*>(&Tl[lane][k4 * 4]);
#pragma unroll
    for (int g = 0; g < 3; ++g)
#pragma unroll
      for (int hh = 0; hh < 8; ++hh) {
        const float4 wv = *reinterpret_cast<const float4*>(
            &wp[(g * 8 + hh) * 160 + k4 * 4]);
        float a = acc[g][hh];
        a = fmaf(t.x, wv.x, a);
        a = fmaf(t.y, wv.y, a);
        a = fmaf(t.z, wv.z, a);
        a = fmaf(t.w, wv.w, a);
        acc[g][hh] = a;
      }
  }

#pragma unroll
  for (int hh = 0; hh < 8; ++hh) {
    int h = w * 8 + hh;
    float pi = acc[0][hh] + be[h];
    float pc = acc[1][hh] + be[32 + h];
    float po = acc[2][hh] + be[64 + h];
    float I = 1.f / (1.f + expf(-pi));
    float Cn = I * tanhf(pc);
    float O = 1.f / (1.f + expf(-(po + wc2[h] * Cn)));
    Hl[lane][h] = fmaxf(O * tanhf(Cn), 0.f);
  }
  __syncthreads();

  for (int q = tid; q < 2048; q += 256) {  // 64 nodes x 32 feats
    int node = q >> 5, f = q & 31;
    int gn = base + node;
    if (gn < n) Hout[gn * 32 + f] = Hl[node][f];
  }
}

// ---- head: out[n] = H2[n,:] . w_eff + b_eff -------------------------------
__global__ __launch_bounds__(TPB) void k_head(
    const float* __restrict__ H, const float* __restrict__ weff,
    float* __restrict__ out, int n) {
  int i = blockIdx.x * TPB + threadIdx.x;
  if (i >= n) return;
  const float4* hp = reinterpret_cast<const float4*>(H + i * 32);
  float s = weff[32];
#pragma unroll
  for (int q = 0; q < 8; ++q) {
    float4 v = hp[q];
    s = fmaf(v.x, weff[q * 4 + 0], s);
    s = fmaf(v.y, weff[q * 4 + 1], s);
    s = fmaf(v.z, weff[q * 4 + 2], s);
    s = fmaf(v.w, weff[q * 4 + 3], s);
  }
  out[i] = s;
}

extern "C" void kernel_launch(void* const* d_in, const int* in_sizes, int n_in,
                              void* d_out, int out_size, void* d_ws,
                              size_t ws_size, hipStream_t stream) {
  const float* x = (const float*)d_in[0];
  const int* ei = (const int*)d_in[1];
  const float* ew = (const float*)d_in[2];
  const float* l1_Wx = (const float*)d_in[3];
  const float* l1_bx = (const float*)d_in[4];
  const float* l1_bh = (const float*)d_in[6];
  const float* l1_wc = (const float*)d_in[7];
  const float* l1_b = (const float*)d_in[8];
  const float* l2_Wx = (const float*)d_in[9];
  const float* l2_bx = (const float*)d_in[10];
  const float* l2_bh = (const float*)d_in[12];
  const float* l2_wc = (const float*)d_in[13];
  const float* l2_b = (const float*)d_in[14];
  const float* hw1 = (const float*)d_in[15];
  const float* hb1 = (const float*)d_in[16];
  const float* hw2 = (const float*)d_in[17];
  const float* hb2 = (const float*)d_in[18];
  const float* hw3 = (const float*)d_in[19];
  const float* hb3 = (const float*)d_in[20];
  const float* hw4 = (const float*)d_in[21];
  const float* hb4 = (const float*)d_in[22];

  const int N = in_sizes[0] / 32;
  const int E = in_sizes[1] / 2;
  const size_t EPAD = (size_t)E + 16 * (size_t)N;  // padded CSR capacity

  // workspace carve-out (256B aligned)
  char* w = (char*)d_ws;
  auto alloc = [&](size_t bytes) -> void* {
    void* p = (void*)w;
    w += (bytes + 255) & ~(size_t)255;
    return p;
  };
  float* dinv = (float*)alloc((size_t)N * 4);
  int* cnt = (int*)alloc((size_t)N * 4);
  int* rp = (int*)alloc((size_t)(N + 1) * 4);
  int* excl = (int*)alloc((size_t)N * 4);
  int* bsum = (int*)alloc(256 * 4);
  int* dcnt = (int*)alloc(512 * 4);  // contiguous with scnt: single memset
  int* scnt = (int*)alloc(512 * 4);
  uint2* epk = (uint2*)alloc(EPAD * 8);
  float* T1 = (float*)alloc((size_t)N * 32 * 4);
  float* T2 = (float*)alloc((size_t)N * 32 * 4);
  float* T3 = (float*)alloc((size_t)N * 32 * 4);
  float* T4 = (float*)alloc((size_t)N * 32 * 4);
  float* H1 = (float*)alloc((size_t)N * 32 * 4);
  float* H2 = (float*)alloc((size_t)N * 32 * 4);
  float* Wt1 = (float*)alloc(160 * 96 * 4);
  float* be1 = (float*)alloc(96 * 4);
  float* Wt2 = (float*)alloc(160 * 96 * 4);
  float* be2 = (float*)alloc(96 * 4);
  float* weff = (float*)alloc(40 * 4);
  // arenas overlay T/H buffers (dead until props): NB*CAP*8 = 18.82MB each
  uint2* arS = (uint2*)T1;
  uint2* arD = (uint2*)T4;

  const int gBK = (E + EPB - 1) / EPB;
  const int gN = (N + TPB - 1) / TPB;
  const int gP = (N + 3) / 4;
  const int gG = (N + 63) / 64;

  hipMemsetAsync(dcnt, 0, 1024 * 4, stream);  // dcnt + scnt
  hipMemsetAsync(epk, 0, EPAD * 8, stream);   // zero pads

  // CSR build (two-level LDS counting sort)
  k_bucket<<<gBK, 512, 0, stream>>>(ei, ew, dcnt, scnt, arD, arS, E);
  k_deg<<<NB, TPB, 0, stream>>>(arS, scnt, dinv, N);
  k_cnt<<<NB, TPB, 0, stream>>>(arD, dcnt, cnt, N);
  k_scan1<<<gN, TPB, 0, stream>>>(cnt, excl, bsum, N);
  k_scan2<<<1, TPB, 0, stream>>>(bsum, gN);
  k_scan3<<<gN, TPB, 0, stream>>>(excl, bsum, cnt, rp, N);
  k_csr<<<NB, TPB, 0, stream>>>(arD, dcnt, rp, dinv, epk, N);

  // weight prep
  k_build_wt<<<60, TPB, 0, stream>>>(l1_Wx, l1_bx, l1_bh, l1_b, Wt1, be1);
  k_build_wt<<<60, TPB, 0, stream>>>(l2_Wx, l2_bx, l2_bh, l2_b, Wt2, be2);
  k_head_setup<<<1, 64, 0, stream>>>(hw1, hb1, hw2, hb2, hw3, hb3, hw4, hb4,
                                     weff);

  // layer 1 (T0 = x)
  k_prop<<<gP, TPB, 0, stream>>>(x, rp, epk, nullptr, 1.f, 0.f, T1, N);
  k_prop<<<gP, TPB, 0, stream>>>(T1, rp, epk, x, 2.f, -1.f, T2, N);
  k_prop<<<gP, TPB, 0, stream>>>(T2, rp, epk, T1, 2.f, -1.f, T3, N);
  k_prop<<<gP, TPB, 0, stream>>>(T3, rp, epk, T2, 2.f, -1.f, T4, N);
  k_gates<<<gG, 256, 0, stream>>>(x, T1, T2, T3, T4, Wt1, be1, l1_wc + 64, H1,
                                  N);

  // layer 2 (T0 = H1)
  k_prop<<<gP, TPB, 0, stream>>>(H1, rp, epk, nullptr, 1.f, 0.f, T1, N);
  k_prop<<<gP, TPB, 0, stream>>>(T1, rp, epk, H1, 2.f, -1.f, T2, N);
  k_prop<<<gP, TPB, 0, stream>>>(T2, rp, epk, T1, 2.f, -1.f, T3, N);
  k_prop<<<gP, TPB, 0, stream>>>(T3, rp, epk, T2, 2.f, -1.f, T4, N);
  k_gates<<<gG, 256, 0, stream>>>(H1, T1, T2, T3, T4, Wt2, be2, l2_wc + 64, H2,
                                  N);

  // head
  k_head<<<gN, TPB, 0, stream>>>(H2, weff, (float*)d_out, N);
}